// Round 4
// baseline (1800.523 us; speedup 1.0000x reference)
//
#include <hip/hip_runtime.h>
#include <hip/hip_bf16.h>
#include <math.h>

#define E_TOT 65536
#define B_G   128

// ---------------- generic GEMM: out[n,m] (+)= sum_k X[n,k]*W[k*ldW + col0 + m] + b[col0+m] ----
// flags: bit0 = relu, bit1 = accumulate into out
template <int ROWS>
__global__ void gemm_rows(const float* __restrict__ X, const float* __restrict__ W,
                          const float* __restrict__ bias, float* __restrict__ out,
                          int N, int K, int Mout, int ldW, int col0, int flags) {
    extern __shared__ float xs[];
    int n0 = blockIdx.y * ROWS;
    for (int i = threadIdx.x; i < ROWS * K; i += blockDim.x) {
        int r = i / K, k = i - r * K;
        int n = n0 + r;
        xs[i] = (n < N) ? X[(size_t)n * K + k] : 0.f;
    }
    __syncthreads();
    int m = blockIdx.x * blockDim.x + threadIdx.x;
    if (m >= Mout) return;
    float bv = bias ? bias[col0 + m] : 0.f;
    float acc[ROWS];
#pragma unroll
    for (int r = 0; r < ROWS; ++r) {
        int n = n0 + r;
        acc[r] = (flags & 2) ? ((n < N) ? out[(size_t)n * Mout + m] : 0.f) : bv;
    }
    for (int k = 0; k < K; ++k) {
        float w = W[(size_t)k * ldW + col0 + m];
#pragma unroll
        for (int r = 0; r < ROWS; ++r) acc[r] = fmaf(xs[r * K + k], w, acc[r]);
    }
#pragma unroll
    for (int r = 0; r < ROWS; ++r) {
        int n = n0 + r;
        if (n < N) {
            float a = acc[r];
            if (flags & 1) a = fmaxf(a, 0.f);
            out[(size_t)n * Mout + m] = a;
        }
    }
}

// ---------------- CSR build ----------------
__global__ void count_k(const int* __restrict__ dst, const int* __restrict__ em,
                        int E, int* __restrict__ counts) {
    int e = blockIdx.x * blockDim.x + threadIdx.x;
    if (e >= E) return;
    if (em && !em[e]) return;
    atomicAdd(&counts[dst[e]], 1);
}

__global__ void scan_k(const int* __restrict__ counts, int* __restrict__ row_start, int N) {
    __shared__ int partial[1024];
    const int T = 1024;
    int t = threadIdx.x;
    int per = (N + T - 1) / T;
    int begin = t * per;
    int end = begin + per; if (end > N) end = N;
    int s = 0;
    for (int i = begin; i < end; ++i) s += counts[i];
    partial[t] = s;
    __syncthreads();
    for (int st = 1; st < T; st <<= 1) {
        int v = 0;
        if (t >= st) v = partial[t - st];
        __syncthreads();
        if (t >= st) partial[t] += v;
        __syncthreads();
    }
    int run = partial[t] - s;
    for (int i = begin; i < end; ++i) { row_start[i] = run; run += counts[i]; }
    if (t == T - 1) row_start[N] = partial[T - 1];
}

__global__ void scatter_k(const int* __restrict__ src, const int* __restrict__ dst,
                          const int* __restrict__ em, int E,
                          const int* __restrict__ row_start, int* __restrict__ cursor,
                          int* __restrict__ col, int* __restrict__ eid) {
    int e = blockIdx.x * blockDim.x + threadIdx.x;
    if (e >= E) return;
    if (em && !em[e]) return;
    int d = dst[e];
    int p = atomicAdd(&cursor[d], 1);
    int pos = row_start[d] + p;
    col[pos] = src[e];
    eid[pos] = e;
}

// ---------------- per-head attention (one block = one node = one wave of 64) --------------
// Qh/Kh/Vh/Oh: [N,128] compact. Also accumulates zOut[node] += O_row . (w1+w3)[head chunk].
__global__ void attn_head_k(const float* __restrict__ Q, const float* __restrict__ K,
                            const float* __restrict__ V,
                            const int* __restrict__ row_start, const int* __restrict__ col,
                            const int* __restrict__ eid,
                            const float* __restrict__ ea, const float* __restrict__ We,
                            const float* __restrict__ Wb, int h,
                            float* __restrict__ Oh, float* __restrict__ zOut) {
    __shared__ float we_s[16 * 128];
    int lane = threadIdx.x;  // 64
    for (int i = lane; i < 16 * 128; i += 64) {
        int d = i >> 7, c = i & 127;
        we_s[i] = We[d * 512 + h * 128 + c];
    }
    __syncthreads();
    int node = blockIdx.x;
    float q0 = Q[(size_t)node * 128 + lane];
    float q1 = Q[(size_t)node * 128 + lane + 64];
    float m = -INFINITY, l = 0.f, a0 = 0.f, a1 = 0.f;
    int beg = row_start[node], end = row_start[node + 1];
    for (int j = beg; j < end; ++j) {
        int s = col[j];
        int e = eid[j];
        const float* ear = ea + (size_t)e * 16;
        float e0 = 0.f, e1 = 0.f;
#pragma unroll
        for (int d = 0; d < 16; ++d) {
            float ad = ear[d];
            e0 = fmaf(ad, we_s[d * 128 + lane], e0);
            e1 = fmaf(ad, we_s[d * 128 + lane + 64], e1);
        }
        float k0 = K[(size_t)s * 128 + lane] + e0;
        float k1 = K[(size_t)s * 128 + lane + 64] + e1;
        float part = q0 * k0 + q1 * k1;
#pragma unroll
        for (int off = 32; off; off >>= 1) part += __shfl_xor(part, off, 64);
        float alpha = part * 0.08838834764831845f;  // 1/sqrt(128)
        float nm = fmaxf(m, alpha);
        float sc = expf(m - nm);      // 0 on first edge (m = -inf)
        float w  = expf(alpha - nm);
        l  = l * sc + w;
        a0 = a0 * sc + w * (V[(size_t)s * 128 + lane] + e0);
        a1 = a1 * sc + w * (V[(size_t)s * 128 + lane + 64] + e1);
        m = nm;
    }
    float inv = 1.f / (l + 1e-16f);
    float o0 = a0 * inv, o1 = a1 * inv;
    Oh[(size_t)node * 128 + lane]      = o0;
    Oh[(size_t)node * 128 + lane + 64] = o1;
    int c0 = h * 128 + lane;
    float w13a = Wb[c0]      + Wb[1024 + c0];
    float w13b = Wb[c0 + 64] + Wb[1024 + c0 + 64];
    float zp = o0 * w13a + o1 * w13b;
#pragma unroll
    for (int off = 32; off; off >>= 1) zp += __shfl_xor(zp, off, 64);
    if (lane == 0) zOut[node] += zp;   // heads are sequential launches; one block per node
}

// ---------------- per-layer skip-side vectors ----------------
// ws_z[f] = sum_c Ws[f,c]*(w2-w3)[c];  sbt[m] = sum_c bs[c]*tW[c,m];  zb = sum_c bs[c]*(w2-w3)[c]
__global__ void skip_vecs_k(const float* __restrict__ Ws, const float* __restrict__ bs,
                            const float* __restrict__ tW, const float* __restrict__ Wb,
                            int Fin, float* __restrict__ ws_z, float* __restrict__ sbt,
                            float* __restrict__ zb) {
    int t = threadIdx.x;  // 256
    if (t < Fin) {
        float s = 0.f;
        for (int c = 0; c < 512; ++c)
            s = fmaf(Ws[(size_t)t * 512 + c], Wb[512 + c] - Wb[1024 + c], s);
        ws_z[t] = s;
    }
    if (t >= 128 && t < 256) {
        int m = t - 128;
        float s = 0.f;
        for (int c = 0; c < 512; ++c)
            s = fmaf(bs[c], tW[(size_t)c * 128 + m], s);
        sbt[m] = s;
    }
    if (t == 0) {
        float s = 0.f;
        for (int c = 0; c < 512; ++c)
            s = fmaf(bs[c], Wb[512 + c] - Wb[1024 + c], s);
        zb[0] = s;
    }
}

// ---------------- combine: x_next = relu(beta*(skipT+sbt) + (1-beta)*outT + tb) -------------
__global__ void combine_k(const float* __restrict__ x, int Fin,
                          const float* __restrict__ ws_z, const float* __restrict__ zb,
                          const float* __restrict__ zOut,
                          const float* __restrict__ skipT, const float* __restrict__ sbt,
                          const float* __restrict__ outT, const float* __restrict__ tb,
                          float* __restrict__ xn) {
    __shared__ float red[128];
    int node = blockIdx.x, t = threadIdx.x;  // 128
    red[t] = (t < Fin) ? x[(size_t)node * Fin + t] * ws_z[t] : 0.f;
    __syncthreads();
    for (int st = 64; st; st >>= 1) {
        if (t < st) red[t] += red[t + st];
        __syncthreads();
    }
    float z = zOut[node] + red[0] + zb[0];
    float beta = 1.f / (1.f + expf(-z));
    float a = beta * (skipT[(size_t)node * 128 + t] + sbt[t])
            + (1.f - beta) * outT[(size_t)node * 128 + t] + tb[t];
    xn[(size_t)node * 128 + t] = fmaxf(a, 0.f);
}

// ---------------- batchnorm ----------------
__global__ void bn_stats_k(const float* __restrict__ x, int N, float* __restrict__ stats) {
    int c = threadIdx.x;  // 128
    float s = 0.f, ss = 0.f;
    for (int n = blockIdx.x; n < N; n += gridDim.x) {
        float v = x[(size_t)n * 128 + c];
        s += v; ss += v * v;
    }
    atomicAdd(&stats[c], s);
    atomicAdd(&stats[128 + c], ss);
}

__global__ void bn_apply_k(float* __restrict__ x, int N, const float* __restrict__ stats,
                           const float* __restrict__ g, const float* __restrict__ b) {
    int idx = blockIdx.x * blockDim.x + threadIdx.x;
    if (idx >= N * 128) return;
    int c = idx & 127;
    float m = stats[c] / (float)N;
    float var = fmaxf(stats[128 + c] / (float)N - m * m, 0.f);
    float inv = rsqrtf(var + 1e-5f);
    x[idx] = g[c] * (x[idx] - m) * inv + b[c];
}

// ---------------- pooling ----------------
__global__ void norm_k(const float* __restrict__ w, float* __restrict__ out) {
    __shared__ float red[128];
    float v = w[threadIdx.x];
    red[threadIdx.x] = v * v;
    __syncthreads();
    for (int st = 64; st; st >>= 1) {
        if (threadIdx.x < st) red[threadIdx.x] += red[threadIdx.x + st];
        __syncthreads();
    }
    if (threadIdx.x == 0) out[0] = sqrtf(red[0]);
}

__global__ void score_k(const float* __restrict__ x, const float* __restrict__ w,
                        const float* __restrict__ norm, float* __restrict__ s, int N) {
    int node = blockIdx.x * 4 + (threadIdx.x >> 6);
    int lane = threadIdx.x & 63;
    if (node >= N) return;
    float p = x[(size_t)node * 128 + lane] * w[lane] +
              x[(size_t)node * 128 + lane + 64] * w[lane + 64];
#pragma unroll
    for (int off = 32; off; off >>= 1) p += __shfl_xor(p, off, 64);
    if (lane == 0) s[node] = p / norm[0];
}

// one block per graph; thread t = local node t. Stable top-k (lower index wins on ties).
__global__ void topk_k(const float* __restrict__ s, int n, int k,
                       int* __restrict__ keep, int* __restrict__ newid,
                       int* __restrict__ oon, float* __restrict__ tanhs) {
    __shared__ float ls[128];
    __shared__ int lk[128];
    int g = blockIdx.x, t = threadIdx.x;
    int node = g * n + t;
    float val = (t < n) ? s[node] : -INFINITY;
    ls[t] = val;
    __syncthreads();
    int cnt = 0;
    if (t < n) {
        for (int j = 0; j < n; ++j) {
            float vj = ls[j];
            if (vj > val || (vj == val && j < t)) ++cnt;
        }
    }
    int kp = (t < n && cnt < k) ? 1 : 0;
    lk[t] = kp;
    __syncthreads();
    if (t < n) {
        int rank = 0;
        for (int j = 0; j < t; ++j) rank += lk[j];
        keep[node] = kp;
        if (kp) {
            int nid = g * k + rank;
            newid[node] = nid;
            oon[nid] = node;
            tanhs[node] = tanhf(val);
        } else {
            newid[node] = 0;
        }
    }
}

__global__ void gather_k(const float* __restrict__ x, const int* __restrict__ oon,
                         const float* __restrict__ tanhs, float* __restrict__ xo) {
    int nn = blockIdx.x;
    int c = threadIdx.x;  // 128
    int old = oon[nn];
    xo[(size_t)nn * 128 + c] = x[(size_t)old * 128 + c] * tanhs[old];
}

__global__ void readout_k(const float* __restrict__ x, int k, float* __restrict__ rep) {
    int g = blockIdx.x;
    int c = threadIdx.x;  // 128
    float mx = -INFINITY, sm = 0.f;
    for (int r = 0; r < k; ++r) {
        float v = x[(size_t)(g * k + r) * 128 + c];
        mx = fmaxf(mx, v);
        sm += v;
    }
    rep[g * 256 + c] = mx;
    rep[g * 256 + 128 + c] = sm / (float)k;
}

__global__ void remap_k(const int* __restrict__ src, const int* __restrict__ dst,
                        const int* __restrict__ keep, const int* __restrict__ newid,
                        int* __restrict__ src1, int* __restrict__ dst1, int* __restrict__ em1) {
    int e = blockIdx.x * blockDim.x + threadIdx.x;
    if (e >= E_TOT) return;
    int s_ = src[e], d_ = dst[e];
    int m = (keep[s_] && keep[d_]) ? 1 : 0;
    em1[e] = m;
    src1[e] = m ? newid[s_] : 0;
    dst1[e] = m ? newid[d_] : 0;
}

// ---------------- MLP head: one block per graph, fp32 output ----------------
__global__ void head_k(const float* __restrict__ rep0, const float* __restrict__ rep1,
                       const float* __restrict__ W1, const float* __restrict__ b1,
                       const float* __restrict__ W2, const float* __restrict__ b2,
                       const float* __restrict__ W3, const float* __restrict__ b3,
                       float* __restrict__ out) {
    __shared__ float h[256], a1[256], a2[128], red[256];
    int g = blockIdx.x, t = threadIdx.x;  // 256
    h[t] = rep0[g * 256 + t] + rep1[g * 256 + t];
    __syncthreads();
    float acc = b1[t];
    for (int i = 0; i < 256; ++i) acc = fmaf(h[i], W1[i * 256 + t], acc);
    a1[t] = fmaxf(acc, 0.f);
    __syncthreads();
    if (t < 128) {
        float a = b2[t];
        for (int i = 0; i < 256; ++i) a = fmaf(a1[i], W2[i * 128 + t], a);
        a2[t] = fmaxf(a, 0.f);
    }
    __syncthreads();
    red[t] = (t < 128) ? a2[t] * W3[t] : 0.f;
    __syncthreads();
    for (int st = 128; st; st >>= 1) {
        if (t < st) red[t] += red[t + st];
        __syncthreads();
    }
    if (t == 0) out[g] = red[0] + b3[0];
}

// ======================================================================================
extern "C" void kernel_launch(void* const* d_in, const int* in_sizes, int n_in,
                              void* d_out, int out_size, void* d_ws, size_t ws_size,
                              hipStream_t stream) {
    (void)in_sizes; (void)n_in; (void)out_size; (void)ws_size;

    // ALL float inputs are fp32 (reference setup_inputs uses jnp.float32 throughout).
    const float* x0    = (const float*)d_in[0];
    const int*   ei    = (const int*)d_in[1];
    const float* ea    = (const float*)d_in[2];
    const float* c1_Wq = (const float*)d_in[3];
    const float* c1_bq = (const float*)d_in[4];
    const float* c1_Wk = (const float*)d_in[5];
    const float* c1_bk = (const float*)d_in[6];
    const float* c1_Wv = (const float*)d_in[7];
    const float* c1_bv = (const float*)d_in[8];
    const float* c1_We = (const float*)d_in[9];
    const float* c1_Ws = (const float*)d_in[10];
    const float* c1_bs = (const float*)d_in[11];
    const float* c1_Wb = (const float*)d_in[12];
    const float* t1_W  = (const float*)d_in[13];
    const float* t1_b  = (const float*)d_in[14];
    const float* bn1_g = (const float*)d_in[15];
    const float* bn1_b = (const float*)d_in[16];
    const float* cl_Wq = (const float*)d_in[17];
    const float* cl_bq = (const float*)d_in[18];
    const float* cl_Wk = (const float*)d_in[19];
    const float* cl_bk = (const float*)d_in[20];
    const float* cl_Wv = (const float*)d_in[21];
    const float* cl_bv = (const float*)d_in[22];
    const float* cl_We = (const float*)d_in[23];
    const float* cl_Ws = (const float*)d_in[24];
    const float* cl_bs = (const float*)d_in[25];
    const float* cl_Wb = (const float*)d_in[26];
    const float* tl_W  = (const float*)d_in[27];
    const float* tl_b  = (const float*)d_in[28];
    const float* bnl_g = (const float*)d_in[29];
    const float* bnl_b = (const float*)d_in[30];
    const float* pool_w= (const float*)d_in[31];
    const float* l1_W  = (const float*)d_in[32];
    const float* l1_b  = (const float*)d_in[33];
    const float* l2_W  = (const float*)d_in[34];
    const float* l2_b  = (const float*)d_in[35];
    const float* l3_W  = (const float*)d_in[36];
    const float* l3_b  = (const float*)d_in[37];
    float* out = (float*)d_out;

    // -------- workspace layout (~75 MB) --------
    char* base = (char*)d_ws;
    size_t off = 0;
    auto alloc = [&](size_t bytes) -> void* {
        void* p = base + off;
        off += (bytes + 255) & ~(size_t)255;
        return p;
    };
    float* Qh   = (float*)alloc((size_t)16384 * 128 * 4);  // 8.4 MB each
    float* Kh   = (float*)alloc((size_t)16384 * 128 * 4);
    float* Vh   = (float*)alloc((size_t)16384 * 128 * 4);
    float* Oh   = (float*)alloc((size_t)16384 * 128 * 4);
    float* outT = (float*)alloc((size_t)16384 * 128 * 4);
    float* skpT = (float*)alloc((size_t)16384 * 128 * 4);
    float* xA   = (float*)alloc((size_t)16384 * 128 * 4);
    float* xB   = (float*)alloc((size_t)16384 * 128 * 4);
    float* xp   = (float*)alloc((size_t)8192 * 128 * 4);
    float* xp2  = (float*)alloc((size_t)4096 * 128 * 4);
    float* zOut = (float*)alloc(16384 * 4);
    float* Wst  = (float*)alloc(128 * 128 * 4);
    float* ws_z = (float*)alloc(128 * 4);
    float* sbt  = (float*)alloc(128 * 4);
    float* zb   = (float*)alloc(4 * 4);
    float* stats  = (float*)alloc(256 * 4);
    float* normb  = (float*)alloc(4 * 4);
    float* scores = (float*)alloc(16384 * 4);
    float* tanhs  = (float*)alloc(16384 * 4);
    float* rep0   = (float*)alloc(128 * 256 * 4);
    float* rep1   = (float*)alloc(128 * 256 * 4);
    int* row_start = (int*)alloc(16385 * 4);
    int* counts    = (int*)alloc(16384 * 4);
    int* colb      = (int*)alloc(E_TOT * 4);
    int* eidb      = (int*)alloc(E_TOT * 4);
    int* src1      = (int*)alloc(E_TOT * 4);
    int* dst1      = (int*)alloc(E_TOT * 4);
    int* em1       = (int*)alloc(E_TOT * 4);
    int* keep      = (int*)alloc(16384 * 4);
    int* newid     = (int*)alloc(16384 * 4);
    int* oon       = (int*)alloc(8192 * 4);

    const int ROWS = 8;

    auto gemm = [&](const float* X, const float* W, int N, int K, int Mout, int ldW, int col0,
                    const float* b, float* o, int flags) {
        dim3 grid((Mout + 255) / 256, (N + ROWS - 1) / ROWS);
        size_t lds = (size_t)ROWS * K * 4;
        gemm_rows<8><<<grid, 256, lds, stream>>>(X, W, b, o, N, K, Mout, ldW, col0, flags);
    };

    auto build_csr = [&](const int* srcp, const int* dstp, const int* emp, int N) {
        hipMemsetAsync(counts, 0, (size_t)N * 4, stream);
        count_k<<<E_TOT / 256, 256, 0, stream>>>(dstp, emp, E_TOT, counts);
        scan_k<<<1, 1024, 0, stream>>>(counts, row_start, N);
        hipMemsetAsync(counts, 0, (size_t)N * 4, stream);
        scatter_k<<<E_TOT / 256, 256, 0, stream>>>(srcp, dstp, emp, E_TOT, row_start, counts, colb, eidb);
    };

    // Full tconv + t-layer(+bias+relu): xn = relu(gated @ tW + tb)
    auto tconv = [&](const float* xin, int N, int Fin,
                     const float* Wq, const float* bq, const float* Wk, const float* bk,
                     const float* Wv, const float* bv, const float* We,
                     const float* Ws, const float* bs, const float* Wb,
                     const float* tW, const float* tb, float* xn) {
        hipMemsetAsync(zOut, 0, (size_t)N * 4, stream);
        hipMemsetAsync(outT, 0, (size_t)N * 128 * 4, stream);
        // composed skip weights: Wst = Ws @ tW   [Fin,128]
        gemm(Ws, tW, Fin, 512, 128, 128, 0, nullptr, Wst, 0);
        skip_vecs_k<<<1, 256, 0, stream>>>(Ws, bs, tW, Wb, Fin, ws_z, sbt, zb);
        // skipT = x @ Wst
        gemm(xin, Wst, N, Fin, 128, 128, 0, nullptr, skpT, 0);
        for (int h = 0; h < 4; ++h) {
            gemm(xin, Wq, N, Fin, 128, 512, h * 128, bq, Qh, 0);
            gemm(xin, Wk, N, Fin, 128, 512, h * 128, bk, Kh, 0);
            gemm(xin, Wv, N, Fin, 128, 512, h * 128, bv, Vh, 0);
            attn_head_k<<<N, 64, 0, stream>>>(Qh, Kh, Vh, row_start, colb, eidb, ea, We, Wb, h, Oh, zOut);
            // outT += Oh @ tW[h*128:(h+1)*128, :]
            gemm(Oh, tW + (size_t)h * 128 * 128, N, 128, 128, 128, 0, nullptr, outT, 2);
        }
        combine_k<<<N, 128, 0, stream>>>(xin, Fin, ws_z, zb, zOut, skpT, sbt, outT, tb, xn);
    };

    auto bn = [&](float* x, int N, const float* g, const float* b) {
        hipMemsetAsync(stats, 0, 256 * 4, stream);
        bn_stats_k<<<128, 128, 0, stream>>>(x, N, stats);
        bn_apply_k<<<(N * 128 + 255) / 256, 256, 0, stream>>>(x, N, stats, g, b);
    };

    // ---- CSR over original edges (used by layer 1 and loop layer 0) ----
    build_csr(ei, ei + E_TOT, nullptr, 16384);

    // ---- layer 1: tconv(Fin=64) + t1 + bn1 ----
    tconv(x0, 16384, 64, c1_Wq, c1_bq, c1_Wk, c1_bk, c1_Wv, c1_bv, c1_We,
          c1_Ws, c1_bs, c1_Wb, t1_W, t1_b, xA);
    bn(xA, 16384, bn1_g, bn1_b);

    // ---- loop layer 0 (Fin=128, N=16384) ----
    tconv(xA, 16384, 128, cl_Wq, cl_bq, cl_Wk, cl_bk, cl_Wv, cl_bv, cl_We,
          cl_Ws, cl_bs, cl_Wb, tl_W, tl_b, xB);
    bn(xB, 16384, bnl_g, bnl_b);

    // ---- pool 0 (n=128 -> k=64) ----
    norm_k<<<1, 128, 0, stream>>>(pool_w, normb);
    score_k<<<16384 / 4, 256, 0, stream>>>(xB, pool_w, normb, scores, 16384);
    topk_k<<<B_G, 128, 0, stream>>>(scores, 128, 64, keep, newid, oon, tanhs);
    gather_k<<<8192, 128, 0, stream>>>(xB, oon, tanhs, xp);
    readout_k<<<B_G, 128, 0, stream>>>(xp, 64, rep0);
    remap_k<<<E_TOT / 256, 256, 0, stream>>>(ei, ei + E_TOT, keep, newid, src1, dst1, em1);

    // ---- CSR over remapped edges (8192 nodes) ----
    build_csr(src1, dst1, em1, 8192);

    // ---- loop layer 1 (Fin=128, N=8192) ----
    tconv(xp, 8192, 128,
          cl_Wq + 65536, cl_bq + 512, cl_Wk + 65536, cl_bk + 512,
          cl_Wv + 65536, cl_bv + 512, cl_We + 8192,
          cl_Ws + 65536, cl_bs + 512, cl_Wb + 1536,
          tl_W + 65536, tl_b + 128, xA);
    bn(xA, 8192, bnl_g + 128, bnl_b + 128);

    // ---- pool 1 (n=64 -> k=32) ----
    norm_k<<<1, 128, 0, stream>>>(pool_w + 128, normb);
    score_k<<<8192 / 4, 256, 0, stream>>>(xA, pool_w + 128, normb, scores, 8192);
    topk_k<<<B_G, 128, 0, stream>>>(scores, 64, 32, keep, newid, oon, tanhs);
    gather_k<<<4096, 128, 0, stream>>>(xA, oon, tanhs, xp2);
    readout_k<<<B_G, 128, 0, stream>>>(xp2, 32, rep1);

    // ---- MLP head (fp32 out) ----
    head_k<<<B_G, 256, 0, stream>>>(rep0, rep1, l1_W, l1_b, l2_W, l2_b, l3_W, l3_b, out);
}

// Round 5
// 1309.753 us; speedup vs baseline: 1.3747x; 1.3747x over previous
//
#include <hip/hip_runtime.h>
#include <math.h>

#define E_TOT 65536
#define B_G   128

// ---------------- generic GEMM: out[n,m] (+)= sum_k X[n,k]*W[k*ldW + col0 + m] + b[col0+m] ----
// flags: bit0 = relu, bit1 = accumulate into out. Launch with blockDim = min(Mout,256) rounded
// to a multiple of 64; grid ((Mout+bd-1)/bd, ceil(N/8)); dyn-LDS = 8*K*4.
template <int ROWS>
__global__ void gemm_rows(const float* __restrict__ X, const float* __restrict__ W,
                          const float* __restrict__ bias, float* __restrict__ out,
                          int N, int K, int Mout, int ldW, int col0, int flags) {
    extern __shared__ float xs[];
    int n0 = blockIdx.y * ROWS;
    for (int i = threadIdx.x; i < ROWS * K; i += blockDim.x) {
        int r = i / K, k = i - r * K;
        int n = n0 + r;
        xs[i] = (n < N) ? X[(size_t)n * K + k] : 0.f;
    }
    __syncthreads();
    int m = blockIdx.x * blockDim.x + threadIdx.x;
    if (m >= Mout) return;
    float bv = bias ? bias[col0 + m] : 0.f;
    float acc[ROWS];
#pragma unroll
    for (int r = 0; r < ROWS; ++r) {
        int n = n0 + r;
        acc[r] = (flags & 2) ? ((n < N) ? out[(size_t)n * Mout + m] : 0.f) : bv;
    }
    for (int k = 0; k < K; ++k) {
        float w = W[(size_t)k * ldW + col0 + m];
#pragma unroll
        for (int r = 0; r < ROWS; ++r) acc[r] = fmaf(xs[r * K + k], w, acc[r]);
    }
#pragma unroll
    for (int r = 0; r < ROWS; ++r) {
        int n = n0 + r;
        if (n < N) {
            float a = acc[r];
            if (flags & 1) a = fmaxf(a, 0.f);
            out[(size_t)n * Mout + m] = a;
        }
    }
}

// ---------------- warp-per-output small GEMM: Wst[f,m] = sum_c Ws[f*512+c]*tW[c*128+m] --------
__global__ void compose_k(const float* __restrict__ Ws, const float* __restrict__ tW,
                          int Fin, float* __restrict__ Wst) {
    int w = (blockIdx.x * blockDim.x + threadIdx.x) >> 6;
    int lane = threadIdx.x & 63;
    if (w >= Fin * 128) return;
    int f = w >> 7, m = w & 127;
    float s = 0.f;
    for (int c = lane; c < 512; c += 64)
        s = fmaf(Ws[(size_t)f * 512 + c], tW[(size_t)c * 128 + m], s);
#pragma unroll
    for (int off = 32; off; off >>= 1) s += __shfl_xor(s, off, 64);
    if (lane == 0) Wst[w] = s;
}

// ws_z[f]=dot(Ws[f,:], w2-w3); sbt[m]=dot(bs, tW[:,m]); zb=dot(bs, w2-w3)   (warp per output)
__global__ void vecs_k(const float* __restrict__ Ws, const float* __restrict__ bs,
                       const float* __restrict__ tW, const float* __restrict__ Wb,
                       int Fin, float* __restrict__ ws_z, float* __restrict__ sbt,
                       float* __restrict__ zb) {
    int w = (blockIdx.x * blockDim.x + threadIdx.x) >> 6;
    int lane = threadIdx.x & 63;
    int total = Fin + 128 + 1;
    if (w >= total) return;
    float s = 0.f;
    if (w < Fin) {
        for (int c = lane; c < 512; c += 64)
            s = fmaf(Ws[(size_t)w * 512 + c], Wb[512 + c] - Wb[1024 + c], s);
    } else if (w < Fin + 128) {
        int m = w - Fin;
        for (int c = lane; c < 512; c += 64)
            s = fmaf(bs[c], tW[(size_t)c * 128 + m], s);
    } else {
        for (int c = lane; c < 512; c += 64)
            s = fmaf(bs[c], Wb[512 + c] - Wb[1024 + c], s);
    }
#pragma unroll
    for (int off = 32; off; off >>= 1) s += __shfl_xor(s, off, 64);
    if (lane == 0) {
        if (w < Fin) ws_z[w] = s;
        else if (w < Fin + 128) sbt[w - Fin] = s;
        else zb[0] = s;
    }
}

// ---------------- CSR build ----------------
__global__ void count_k(const int* __restrict__ dst, const int* __restrict__ em,
                        int E, int* __restrict__ counts) {
    int e = blockIdx.x * blockDim.x + threadIdx.x;
    if (e >= E) return;
    if (em && !em[e]) return;
    atomicAdd(&counts[dst[e]], 1);
}

// exclusive scan of counts -> row_start[0..N]; zeroes counts (reused as scatter cursor)
__global__ void scan_k(const int* __restrict__ counts_in, int* __restrict__ row_start, int N,
                       int* __restrict__ counts_clr) {
    __shared__ int partial[1024];
    const int T = 1024;
    int t = threadIdx.x;
    int per = (N + T - 1) / T;
    int begin = t * per;
    int end = begin + per; if (end > N) end = N;
    int s = 0;
    for (int i = begin; i < end; ++i) s += counts_in[i];
    partial[t] = s;
    __syncthreads();
    for (int st = 1; st < T; st <<= 1) {
        int v = 0;
        if (t >= st) v = partial[t - st];
        __syncthreads();
        if (t >= st) partial[t] += v;
        __syncthreads();
    }
    int run = partial[t] - s;
    for (int i = begin; i < end; ++i) {
        row_start[i] = run; run += counts_in[i]; counts_clr[i] = 0;
    }
    if (t == T - 1) row_start[N] = partial[T - 1];
}

__global__ void scatter_k(const int* __restrict__ src, const int* __restrict__ dst,
                          const int* __restrict__ em, int E,
                          const int* __restrict__ row_start, int* __restrict__ cursor,
                          int* __restrict__ col, int* __restrict__ eid) {
    int e = blockIdx.x * blockDim.x + threadIdx.x;
    if (e >= E) return;
    if (em && !em[e]) return;
    int d = dst[e];
    int p = atomicAdd(&cursor[d], 1);
    int pos = row_start[d] + p;
    col[pos] = src[e];
    eid[pos] = e;
}

// ---------------- all-heads attention: block=256 (4 waves, wave=head), R nodes per block -----
// QO: [N,512] holds Q on entry, O on exit (in-place: each wave reads only its own node's Q row
// fully before writing O). Kb/Vb: [N,512]. zOut[node] = sum_h O_h . (w1+w3)_h  (fresh write).
template <int R>
__global__ void attn_all_k(float* __restrict__ QO, const float* __restrict__ Kb,
                           const float* __restrict__ Vb,
                           const int* __restrict__ row_start, const int* __restrict__ col,
                           const int* __restrict__ eid,
                           const float* __restrict__ ea, const float* __restrict__ We,
                           const float* __restrict__ Wb, float* __restrict__ zOut) {
    __shared__ float we_s[16 * 512];    // 32 KB
    __shared__ float zsh[R][4];
    int tid = threadIdx.x;
    int h = tid >> 6, lane = tid & 63;
    for (int i = tid; i < 16 * 512; i += 256) we_s[i] = We[i];
    __syncthreads();
    int base = blockIdx.x * R;
    int c0 = h * 128 + lane, c1 = c0 + 64;
    float w13a = Wb[c0] + Wb[1024 + c0];
    float w13b = Wb[c1] + Wb[1024 + c1];
    for (int r = 0; r < R; ++r) {
        int node = base + r;
        float q0 = QO[(size_t)node * 512 + c0];
        float q1 = QO[(size_t)node * 512 + c1];
        float m = -INFINITY, l = 0.f, a0 = 0.f, a1 = 0.f;
        int beg = row_start[node], end = row_start[node + 1];
        for (int j = beg; j < end; ++j) {
            int s = col[j];
            int e = eid[j];
            const float* ear = ea + (size_t)e * 16;
            float e0 = 0.f, e1 = 0.f;
#pragma unroll
            for (int d = 0; d < 16; ++d) {
                float ad = ear[d];
                e0 = fmaf(ad, we_s[d * 512 + c0], e0);
                e1 = fmaf(ad, we_s[d * 512 + c1], e1);
            }
            float k0 = Kb[(size_t)s * 512 + c0] + e0;
            float k1 = Kb[(size_t)s * 512 + c1] + e1;
            float part = q0 * k0 + q1 * k1;
#pragma unroll
            for (int off = 32; off; off >>= 1) part += __shfl_xor(part, off, 64);
            float alpha = part * 0.08838834764831845f;  // 1/sqrt(128)
            float nm = fmaxf(m, alpha);
            float sc = expf(m - nm);
            float w  = expf(alpha - nm);
            l  = l * sc + w;
            a0 = a0 * sc + w * (Vb[(size_t)s * 512 + c0] + e0);
            a1 = a1 * sc + w * (Vb[(size_t)s * 512 + c1] + e1);
            m = nm;
        }
        float inv = 1.f / (l + 1e-16f);
        float o0 = a0 * inv, o1 = a1 * inv;
        QO[(size_t)node * 512 + c0] = o0;
        QO[(size_t)node * 512 + c1] = o1;
        float zp = o0 * w13a + o1 * w13b;
#pragma unroll
        for (int off = 32; off; off >>= 1) zp += __shfl_xor(zp, off, 64);
        if (lane == 0) zsh[r][h] = zp;
        __syncthreads();
        if (tid == 0) zOut[node] = zsh[r][0] + zsh[r][1] + zsh[r][2] + zsh[r][3];
    }
}

// ---------------- per-head attention fallback: block=256 (4 waves, wave=node), head h --------
__global__ void attn_head4_k(const float* __restrict__ Q, const float* __restrict__ K,
                             const float* __restrict__ V,
                             const int* __restrict__ row_start, const int* __restrict__ col,
                             const int* __restrict__ eid,
                             const float* __restrict__ ea, const float* __restrict__ We,
                             const float* __restrict__ Wb, int h, int first,
                             float* __restrict__ Oh, float* __restrict__ zOut) {
    __shared__ float we_s[16 * 128];
    int tid = threadIdx.x;
    int wv = tid >> 6, lane = tid & 63;
    for (int i = tid; i < 16 * 128; i += 256) {
        int d = i >> 7, c = i & 127;
        we_s[i] = We[d * 512 + h * 128 + c];
    }
    __syncthreads();
    int node = blockIdx.x * 4 + wv;
    float q0 = Q[(size_t)node * 128 + lane];
    float q1 = Q[(size_t)node * 128 + lane + 64];
    float m = -INFINITY, l = 0.f, a0 = 0.f, a1 = 0.f;
    int beg = row_start[node], end = row_start[node + 1];
    for (int j = beg; j < end; ++j) {
        int s = col[j];
        int e = eid[j];
        const float* ear = ea + (size_t)e * 16;
        float e0 = 0.f, e1 = 0.f;
#pragma unroll
        for (int d = 0; d < 16; ++d) {
            float ad = ear[d];
            e0 = fmaf(ad, we_s[d * 128 + lane], e0);
            e1 = fmaf(ad, we_s[d * 128 + lane + 64], e1);
        }
        float k0 = K[(size_t)s * 128 + lane] + e0;
        float k1 = K[(size_t)s * 128 + lane + 64] + e1;
        float part = q0 * k0 + q1 * k1;
#pragma unroll
        for (int off = 32; off; off >>= 1) part += __shfl_xor(part, off, 64);
        float alpha = part * 0.08838834764831845f;
        float nm = fmaxf(m, alpha);
        float sc = expf(m - nm);
        float w  = expf(alpha - nm);
        l  = l * sc + w;
        a0 = a0 * sc + w * (V[(size_t)s * 128 + lane] + e0);
        a1 = a1 * sc + w * (V[(size_t)s * 128 + lane + 64] + e1);
        m = nm;
    }
    float inv = 1.f / (l + 1e-16f);
    float o0 = a0 * inv, o1 = a1 * inv;
    Oh[(size_t)node * 128 + lane]      = o0;
    Oh[(size_t)node * 128 + lane + 64] = o1;
    int c0 = h * 128 + lane;
    float zp = o0 * (Wb[c0] + Wb[1024 + c0]) + o1 * (Wb[c0 + 64] + Wb[1024 + c0 + 64]);
#pragma unroll
    for (int off = 32; off; off >>= 1) zp += __shfl_xor(zp, off, 64);
    if (lane == 0) zOut[node] = (first ? 0.f : zOut[node]) + zp;
}

// ---------------- combine: x_next = relu(beta*(skipT+sbt) + (1-beta)*outT + tb) -------------
__global__ void combine_k(const float* __restrict__ x, int Fin,
                          const float* __restrict__ ws_z, const float* __restrict__ zb,
                          const float* __restrict__ zOut,
                          const float* __restrict__ skipT, const float* __restrict__ sbt,
                          const float* __restrict__ outT, const float* __restrict__ tb,
                          float* __restrict__ xn) {
    __shared__ float red[128];
    int node = blockIdx.x, t = threadIdx.x;  // 128
    red[t] = (t < Fin) ? x[(size_t)node * Fin + t] * ws_z[t] : 0.f;
    __syncthreads();
    for (int st = 64; st; st >>= 1) {
        if (t < st) red[t] += red[t + st];
        __syncthreads();
    }
    float z = zOut[node] + red[0] + zb[0];
    float beta = 1.f / (1.f + expf(-z));
    float a = beta * (skipT[(size_t)node * 128 + t] + sbt[t])
            + (1.f - beta) * outT[(size_t)node * 128 + t] + tb[t];
    xn[(size_t)node * 128 + t] = fmaxf(a, 0.f);
}

// ---------------- batchnorm ----------------
__global__ void bn_stats_k(const float* __restrict__ x, int N, float* __restrict__ stats) {
    int c = threadIdx.x;  // 128
    float s = 0.f, ss = 0.f;
    for (int n = blockIdx.x; n < N; n += gridDim.x) {
        float v = x[(size_t)n * 128 + c];
        s += v; ss += v * v;
    }
    atomicAdd(&stats[c], s);
    atomicAdd(&stats[128 + c], ss);
}

__global__ void bn_apply_k(float* __restrict__ x, int N, const float* __restrict__ stats,
                           const float* __restrict__ g, const float* __restrict__ b) {
    int idx = blockIdx.x * blockDim.x + threadIdx.x;
    if (idx >= N * 128) return;
    int c = idx & 127;
    float m = stats[c] / (float)N;
    float var = fmaxf(stats[128 + c] / (float)N - m * m, 0.f);
    float inv = rsqrtf(var + 1e-5f);
    x[idx] = g[c] * (x[idx] - m) * inv + b[c];
}

// ---------------- pooling ----------------
__global__ void score_k(const float* __restrict__ x, const float* __restrict__ w,
                        float* __restrict__ s, int N) {
    int node = blockIdx.x * 4 + (threadIdx.x >> 6);
    int lane = threadIdx.x & 63;
    float w0 = w[lane], w1 = w[lane + 64];
    float p  = x[(size_t)node * 128 + lane] * w0 + x[(size_t)node * 128 + lane + 64] * w1;
    float nw = w0 * w0 + w1 * w1;
#pragma unroll
    for (int off = 32; off; off >>= 1) {
        p  += __shfl_xor(p, off, 64);
        nw += __shfl_xor(nw, off, 64);
    }
    if (lane == 0) s[node] = p / sqrtf(nw);
}

// one block per graph; thread t = local node t. Stable top-k (lower index wins on ties).
__global__ void topk_k(const float* __restrict__ s, int n, int k,
                       int* __restrict__ keep, int* __restrict__ newid,
                       int* __restrict__ oon, float* __restrict__ tanhs) {
    __shared__ float ls[128];
    __shared__ int lk[128];
    int g = blockIdx.x, t = threadIdx.x;
    int node = g * n + t;
    float val = (t < n) ? s[node] : -INFINITY;
    ls[t] = val;
    __syncthreads();
    int cnt = 0;
    if (t < n) {
        for (int j = 0; j < n; ++j) {
            float vj = ls[j];
            if (vj > val || (vj == val && j < t)) ++cnt;
        }
    }
    int kp = (t < n && cnt < k) ? 1 : 0;
    lk[t] = kp;
    __syncthreads();
    if (t < n) {
        int rank = 0;
        for (int j = 0; j < t; ++j) rank += lk[j];
        keep[node] = kp;
        if (kp) {
            int nid = g * k + rank;
            newid[node] = nid;
            oon[nid] = node;
            tanhs[node] = tanhf(val);
        } else {
            newid[node] = 0;
        }
    }
}

__global__ void gather_k(const float* __restrict__ x, const int* __restrict__ oon,
                         const float* __restrict__ tanhs, float* __restrict__ xo) {
    int nn = blockIdx.x;
    int c = threadIdx.x;  // 128
    int old = oon[nn];
    xo[(size_t)nn * 128 + c] = x[(size_t)old * 128 + c] * tanhs[old];
}

__global__ void readout_k(const float* __restrict__ x, int k, float* __restrict__ rep) {
    int g = blockIdx.x;
    int c = threadIdx.x;  // 128
    float mx = -INFINITY, sm = 0.f;
    for (int r = 0; r < k; ++r) {
        float v = x[(size_t)(g * k + r) * 128 + c];
        mx = fmaxf(mx, v);
        sm += v;
    }
    rep[g * 256 + c] = mx;
    rep[g * 256 + 128 + c] = sm / (float)k;
}

__global__ void remap_k(const int* __restrict__ src, const int* __restrict__ dst,
                        const int* __restrict__ keep, const int* __restrict__ newid,
                        int* __restrict__ src1, int* __restrict__ dst1, int* __restrict__ em1) {
    int e = blockIdx.x * blockDim.x + threadIdx.x;
    if (e >= E_TOT) return;
    int s_ = src[e], d_ = dst[e];
    int m = (keep[s_] && keep[d_]) ? 1 : 0;
    em1[e] = m;
    src1[e] = m ? newid[s_] : 0;
    dst1[e] = m ? newid[d_] : 0;
}

// ---------------- MLP head: one block per graph, fp32 output ----------------
__global__ void head_k(const float* __restrict__ rep0, const float* __restrict__ rep1,
                       const float* __restrict__ W1, const float* __restrict__ b1,
                       const float* __restrict__ W2, const float* __restrict__ b2,
                       const float* __restrict__ W3, const float* __restrict__ b3,
                       float* __restrict__ out) {
    __shared__ float h[256], a1[256], a2[128], red[256];
    int g = blockIdx.x, t = threadIdx.x;  // 256
    h[t] = rep0[g * 256 + t] + rep1[g * 256 + t];
    __syncthreads();
    float acc = b1[t];
    for (int i = 0; i < 256; ++i) acc = fmaf(h[i], W1[i * 256 + t], acc);
    a1[t] = fmaxf(acc, 0.f);
    __syncthreads();
    if (t < 128) {
        float a = b2[t];
        for (int i = 0; i < 256; ++i) a = fmaf(a1[i], W2[i * 128 + t], a);
        a2[t] = fmaxf(a, 0.f);
    }
    __syncthreads();
    red[t] = (t < 128) ? a2[t] * W3[t] : 0.f;
    __syncthreads();
    for (int st = 128; st; st >>= 1) {
        if (t < st) red[t] += red[t + st];
        __syncthreads();
    }
    if (t == 0) out[g] = red[0] + b3[0];
}

// ======================================================================================
extern "C" void kernel_launch(void* const* d_in, const int* in_sizes, int n_in,
                              void* d_out, int out_size, void* d_ws, size_t ws_size,
                              hipStream_t stream) {
    (void)in_sizes; (void)n_in; (void)out_size;

    const float* x0    = (const float*)d_in[0];
    const int*   ei    = (const int*)d_in[1];
    const float* ea    = (const float*)d_in[2];
    const float* c1_Wq = (const float*)d_in[3];
    const float* c1_bq = (const float*)d_in[4];
    const float* c1_Wk = (const float*)d_in[5];
    const float* c1_bk = (const float*)d_in[6];
    const float* c1_Wv = (const float*)d_in[7];
    const float* c1_bv = (const float*)d_in[8];
    const float* c1_We = (const float*)d_in[9];
    const float* c1_Ws = (const float*)d_in[10];
    const float* c1_bs = (const float*)d_in[11];
    const float* c1_Wb = (const float*)d_in[12];
    const float* t1_W  = (const float*)d_in[13];
    const float* t1_b  = (const float*)d_in[14];
    const float* bn1_g = (const float*)d_in[15];
    const float* bn1_b = (const float*)d_in[16];
    const float* cl_Wq = (const float*)d_in[17];
    const float* cl_bq = (const float*)d_in[18];
    const float* cl_Wk = (const float*)d_in[19];
    const float* cl_bk = (const float*)d_in[20];
    const float* cl_Wv = (const float*)d_in[21];
    const float* cl_bv = (const float*)d_in[22];
    const float* cl_We = (const float*)d_in[23];
    const float* cl_Ws = (const float*)d_in[24];
    const float* cl_bs = (const float*)d_in[25];
    const float* cl_Wb = (const float*)d_in[26];
    const float* tl_W  = (const float*)d_in[27];
    const float* tl_b  = (const float*)d_in[28];
    const float* bnl_g = (const float*)d_in[29];
    const float* bnl_b = (const float*)d_in[30];
    const float* pool_w= (const float*)d_in[31];
    const float* l1_W  = (const float*)d_in[32];
    const float* l1_b  = (const float*)d_in[33];
    const float* l2_W  = (const float*)d_in[34];
    const float* l2_b  = (const float*)d_in[35];
    const float* l3_W  = (const float*)d_in[36];
    const float* l3_b  = (const float*)d_in[37];
    float* out = (float*)d_out;

    // -------- workspace layout --------
    char* base = (char*)d_ws;
    size_t off = 0;
    auto alloc = [&](size_t bytes) -> void* {
        void* p = base + off;
        off += (bytes + 255) & ~(size_t)255;
        return p;
    };
    // common (~43 MB)
    float* outT = (float*)alloc((size_t)16384 * 128 * 4);
    float* skpT = (float*)alloc((size_t)16384 * 128 * 4);
    float* xA   = (float*)alloc((size_t)16384 * 128 * 4);
    float* xB   = (float*)alloc((size_t)16384 * 128 * 4);
    float* xp   = (float*)alloc((size_t)8192 * 128 * 4);
    float* xp2  = (float*)alloc((size_t)4096 * 128 * 4);
    float* zOut = (float*)alloc(16384 * 4);
    float* Wst  = (float*)alloc(128 * 128 * 4);
    float* ws_z = (float*)alloc(128 * 4);
    float* sbt  = (float*)alloc(128 * 4);
    float* zb   = (float*)alloc(4 * 4);
    float* stats  = (float*)alloc(256 * 4);
    float* scores = (float*)alloc(16384 * 4);
    float* tanhs  = (float*)alloc(16384 * 4);
    float* rep0   = (float*)alloc(128 * 256 * 4);
    float* rep1   = (float*)alloc(128 * 256 * 4);
    int* row_start = (int*)alloc(16385 * 4);
    int* counts    = (int*)alloc(16384 * 4);
    int* colb      = (int*)alloc(E_TOT * 4);
    int* eidb      = (int*)alloc(E_TOT * 4);
    int* src1      = (int*)alloc(E_TOT * 4);
    int* dst1      = (int*)alloc(E_TOT * 4);
    int* em1       = (int*)alloc(E_TOT * 4);
    int* keep      = (int*)alloc(16384 * 4);
    int* newid     = (int*)alloc(16384 * 4);
    int* oon       = (int*)alloc(8192 * 4);

    size_t off_common = off;
    // big path: three [N,512] buffers (+100.7 MB -> ~144 MB total)
    size_t big_end = off_common + 3 * (((size_t)16384 * 512 * 4 + 255) & ~(size_t)255);
    bool big = (big_end <= ws_size);

    float *QO = nullptr, *Kb = nullptr, *Vb = nullptr;       // big path
    float *Qh = nullptr, *Kh = nullptr, *Vh = nullptr, *Oh = nullptr;  // small path
    if (big) {
        QO = (float*)alloc((size_t)16384 * 512 * 4);
        Kb = (float*)alloc((size_t)16384 * 512 * 4);
        Vb = (float*)alloc((size_t)16384 * 512 * 4);
    } else {
        Qh = (float*)alloc((size_t)16384 * 128 * 4);
        Kh = (float*)alloc((size_t)16384 * 128 * 4);
        Vh = (float*)alloc((size_t)16384 * 128 * 4);
        Oh = (float*)alloc((size_t)16384 * 128 * 4);
    }

    auto gemm = [&](const float* X, const float* W, int N, int K, int Mout, int ldW, int col0,
                    const float* b, float* o, int flags, int block) {
        dim3 grid((Mout + block - 1) / block, (N + 7) / 8);
        gemm_rows<8><<<grid, block, (size_t)8 * K * 4, stream>>>(X, W, b, o, N, K, Mout, ldW, col0, flags);
    };

    auto build_csr = [&](const int* srcp, const int* dstp, const int* emp, int N) {
        hipMemsetAsync(counts, 0, (size_t)N * 4, stream);
        count_k<<<E_TOT / 256, 256, 0, stream>>>(dstp, emp, E_TOT, counts);
        scan_k<<<1, 1024, 0, stream>>>(counts, row_start, N, counts);
        scatter_k<<<E_TOT / 256, 256, 0, stream>>>(srcp, dstp, emp, E_TOT, row_start, counts, colb, eidb);
    };

    // Full tconv + t-layer(+bias+relu): xn = relu(gated @ tW + tb)
    auto tconv = [&](const float* xin, int N, int Fin,
                     const float* Wq, const float* bq, const float* Wk, const float* bk,
                     const float* Wv, const float* bv, const float* We,
                     const float* Ws, const float* bs, const float* Wb,
                     const float* tW, const float* tb, float* xn) {
        compose_k<<<(Fin * 128 + 3) / 4, 256, 0, stream>>>(Ws, tW, Fin, Wst);
        vecs_k<<<(Fin + 128 + 1 + 3) / 4, 256, 0, stream>>>(Ws, bs, tW, Wb, Fin, ws_z, sbt, zb);
        gemm(xin, Wst, N, Fin, 128, 128, 0, nullptr, skpT, 0, 128);
        if (big) {
            gemm(xin, Wq, N, Fin, 512, 512, 0, bq, QO, 0, 256);
            gemm(xin, Wk, N, Fin, 512, 512, 0, bk, Kb, 0, 256);
            gemm(xin, Wv, N, Fin, 512, 512, 0, bv, Vb, 0, 256);
            attn_all_k<8><<<N / 8, 256, 0, stream>>>(QO, Kb, Vb, row_start, colb, eidb, ea, We, Wb, zOut);
            gemm(QO, tW, N, 512, 128, 128, 0, nullptr, outT, 0, 128);
        } else {
            for (int h = 0; h < 4; ++h) {
                gemm(xin, Wq, N, Fin, 128, 512, h * 128, bq, Qh, 0, 128);
                gemm(xin, Wk, N, Fin, 128, 512, h * 128, bk, Kh, 0, 128);
                gemm(xin, Wv, N, Fin, 128, 512, h * 128, bv, Vh, 0, 128);
                attn_head4_k<<<N / 4, 256, 0, stream>>>(Qh, Kh, Vh, row_start, colb, eidb,
                                                        ea, We, Wb, h, h == 0 ? 1 : 0, Oh, zOut);
                gemm(Oh, tW + (size_t)h * 128 * 128, N, 128, 128, 128, 0, nullptr, outT,
                     h == 0 ? 0 : 2, 128);
            }
        }
        combine_k<<<N, 128, 0, stream>>>(xin, Fin, ws_z, zb, zOut, skpT, sbt, outT, tb, xn);
    };

    auto bn = [&](float* x, int N, const float* g, const float* b) {
        hipMemsetAsync(stats, 0, 256 * 4, stream);
        bn_stats_k<<<128, 128, 0, stream>>>(x, N, stats);
        bn_apply_k<<<(N * 128 + 255) / 256, 256, 0, stream>>>(x, N, stats, g, b);
    };

    // ---- CSR over original edges (used by layer 1 and loop layer 0) ----
    build_csr(ei, ei + E_TOT, nullptr, 16384);

    // ---- layer 1: tconv(Fin=64) + t1 + bn1 ----
    tconv(x0, 16384, 64, c1_Wq, c1_bq, c1_Wk, c1_bk, c1_Wv, c1_bv, c1_We,
          c1_Ws, c1_bs, c1_Wb, t1_W, t1_b, xA);
    bn(xA, 16384, bn1_g, bn1_b);

    // ---- loop layer 0 (Fin=128, N=16384) ----
    tconv(xA, 16384, 128, cl_Wq, cl_bq, cl_Wk, cl_bk, cl_Wv, cl_bv, cl_We,
          cl_Ws, cl_bs, cl_Wb, tl_W, tl_b, xB);
    bn(xB, 16384, bnl_g, bnl_b);

    // ---- pool 0 (n=128 -> k=64) ----
    score_k<<<16384 / 4, 256, 0, stream>>>(xB, pool_w, scores, 16384);
    topk_k<<<B_G, 128, 0, stream>>>(scores, 128, 64, keep, newid, oon, tanhs);
    gather_k<<<8192, 128, 0, stream>>>(xB, oon, tanhs, xp);
    readout_k<<<B_G, 128, 0, stream>>>(xp, 64, rep0);
    remap_k<<<E_TOT / 256, 256, 0, stream>>>(ei, ei + E_TOT, keep, newid, src1, dst1, em1);

    // ---- CSR over remapped edges (8192 nodes) ----
    build_csr(src1, dst1, em1, 8192);

    // ---- loop layer 1 (Fin=128, N=8192) ----
    tconv(xp, 8192, 128,
          cl_Wq + 65536, cl_bq + 512, cl_Wk + 65536, cl_bk + 512,
          cl_Wv + 65536, cl_bv + 512, cl_We + 8192,
          cl_Ws + 65536, cl_bs + 512, cl_Wb + 1536,
          tl_W + 65536, tl_b + 128, xA);
    bn(xA, 8192, bnl_g + 128, bnl_b + 128);

    // ---- pool 1 (n=64 -> k=32) ----
    score_k<<<8192 / 4, 256, 0, stream>>>(xA, pool_w + 128, scores, 8192);
    topk_k<<<B_G, 128, 0, stream>>>(scores, 64, 32, keep, newid, oon, tanhs);
    gather_k<<<4096, 128, 0, stream>>>(xA, oon, tanhs, xp2);
    readout_k<<<B_G, 128, 0, stream>>>(xp2, 32, rep1);

    // ---- MLP head (fp32 out) ----
    head_k<<<B_G, 256, 0, stream>>>(rep0, rep1, l1_W, l1_b, l2_W, l2_b, l3_W, l3_b, out);
}

// Round 6
// 1137.163 us; speedup vs baseline: 1.5833x; 1.1518x over previous
//
#include <hip/hip_runtime.h>
#include <math.h>

#define E_TOT 65536
#define B_G   128
#define QLD   1664   // fused buffer row: [S(128) | Q(512) | K(512) | V(512)]

// ---------------- fused S/Q/K/V GEMM ----------------
// out[n, col] = sum_k X[n,k] * W(col)[k, lc] + b(col)[lc]
// col<128: Wst(ld128,no bias); <640: Wq; <1152: Wk; <1664: Wv (ld512, bias)
// block 128 threads; each thread 2 cols (col, col+128); ROWS=16 rows per block.
// grid: (7, N/16). LDS: X-tile transposed [KC][ROWS] padded for b128 broadcast reads.
__global__ __launch_bounds__(128) void qkvs_gemm(
        const float* __restrict__ X, int ldX, int K, int kcs,
        const float* __restrict__ Wst,
        const float* __restrict__ Wq, const float* __restrict__ bq,
        const float* __restrict__ Wk, const float* __restrict__ bk,
        const float* __restrict__ Wv, const float* __restrict__ bv,
        float* __restrict__ out) {
    const int ROWS = 16, PAD = 20;
    __shared__ __align__(16) float xs[128 * PAD];
    int tid = threadIdx.x;
    int n0 = blockIdx.y * ROWS;
    int KC = 1 << kcs, kcm = KC - 1;

    int col0 = blockIdx.x * 256 + tid;
    int col1 = col0 + 128;
    bool act1 = col1 < 1664;

    const float* w0; const float* w1;
    int ld0, ld1;
    float b0 = 0.f, b1 = 0.f;
    {
        int c = col0;
        if (c < 128)       { w0 = Wst + c;          ld0 = 128; }
        else if (c < 640)  { w0 = Wq + (c - 128);   ld0 = 512; b0 = bq[c - 128]; }
        else if (c < 1152) { w0 = Wk + (c - 640);   ld0 = 512; b0 = bk[c - 640]; }
        else               { w0 = Wv + (c - 1152);  ld0 = 512; b0 = bv[c - 1152]; }
        c = act1 ? col1 : 0;
        if (c < 128)       { w1 = Wst + c;          ld1 = 128; }
        else if (c < 640)  { w1 = Wq + (c - 128);   ld1 = 512; b1 = bq[c - 128]; }
        else if (c < 1152) { w1 = Wk + (c - 640);   ld1 = 512; b1 = bk[c - 640]; }
        else               { w1 = Wv + (c - 1152);  ld1 = 512; b1 = bv[c - 1152]; }
    }

    float acc0[ROWS], acc1[ROWS];
#pragma unroll
    for (int r = 0; r < ROWS; ++r) { acc0[r] = b0; acc1[r] = b1; }

    for (int k0 = 0; k0 < K; k0 += KC) {
        for (int i = tid; i < ROWS * KC; i += 128) {
            int kk = i & kcm, r = i >> kcs;
            xs[kk * PAD + r] = X[(size_t)(n0 + r) * ldX + k0 + kk];
        }
        __syncthreads();
#pragma unroll 4
        for (int kk = 0; kk < KC; ++kk) {
            const float* xr = xs + kk * PAD;
            float xv[ROWS];
            float4* xvv = (float4*)xv;
            xvv[0] = *(const float4*)(xr);
            xvv[1] = *(const float4*)(xr + 4);
            xvv[2] = *(const float4*)(xr + 8);
            xvv[3] = *(const float4*)(xr + 12);
            float a = *w0; w0 += ld0;
            float b = *w1; w1 += ld1;
#pragma unroll
            for (int r = 0; r < ROWS; ++r) {
                acc0[r] = fmaf(xv[r], a, acc0[r]);
                acc1[r] = fmaf(xv[r], b, acc1[r]);
            }
        }
        __syncthreads();
    }
#pragma unroll
    for (int r = 0; r < ROWS; ++r) {
        out[(size_t)(n0 + r) * QLD + col0] = acc0[r];
        if (act1) out[(size_t)(n0 + r) * QLD + col1] = acc1[r];
    }
}

// ---------------- outT GEMM: out[n,m] = sum_k O[n,k]*tW[k*128+m], K=512, M=128 ----------------
// block 128, ROWS=32, grid.x = N/32. X strided (O region of QKVS), out strided (K region).
__global__ __launch_bounds__(128) void out_gemm(
        const float* __restrict__ X, int ldX,
        const float* __restrict__ W, float* __restrict__ out, int ldOut) {
    const int ROWS = 32, PAD = 36, KC = 128;
    __shared__ __align__(16) float xs[KC * PAD];
    int tid = threadIdx.x;
    int n0 = blockIdx.x * ROWS;
    float acc[ROWS];
#pragma unroll
    for (int r = 0; r < ROWS; ++r) acc[r] = 0.f;
    const float* wp = W + tid;
    for (int k0 = 0; k0 < 512; k0 += KC) {
        for (int i = tid; i < ROWS * KC; i += 128) {
            int kk = i & 127, r = i >> 7;
            xs[kk * PAD + r] = X[(size_t)(n0 + r) * ldX + k0 + kk];
        }
        __syncthreads();
#pragma unroll 2
        for (int kk = 0; kk < KC; ++kk) {
            const float* xr = xs + kk * PAD;
            float xv[ROWS];
            float4* xvv = (float4*)xv;
#pragma unroll
            for (int q = 0; q < 8; ++q) xvv[q] = *(const float4*)(xr + 4 * q);
            float w = *wp; wp += 128;
#pragma unroll
            for (int r = 0; r < ROWS; ++r) acc[r] = fmaf(xv[r], w, acc[r]);
        }
        __syncthreads();
    }
#pragma unroll
    for (int r = 0; r < ROWS; ++r) out[(size_t)(n0 + r) * ldOut + tid] = acc[r];
}

// ---------------- warp-per-output small GEMM: Wst[f,m] = sum_c Ws[f*512+c]*tW[c*128+m] --------
__global__ void compose_k(const float* __restrict__ Ws, const float* __restrict__ tW,
                          int Fin, float* __restrict__ Wst) {
    int w = (blockIdx.x * blockDim.x + threadIdx.x) >> 6;
    int lane = threadIdx.x & 63;
    if (w >= Fin * 128) return;
    int f = w >> 7, m = w & 127;
    float s = 0.f;
    for (int c = lane; c < 512; c += 64)
        s = fmaf(Ws[(size_t)f * 512 + c], tW[(size_t)c * 128 + m], s);
#pragma unroll
    for (int off = 32; off; off >>= 1) s += __shfl_xor(s, off, 64);
    if (lane == 0) Wst[w] = s;
}

// ws_z[f]=dot(Ws[f,:], w2-w3); sbt[m]=dot(bs, tW[:,m]); zb=dot(bs, w2-w3)   (warp per output)
__global__ void vecs_k(const float* __restrict__ Ws, const float* __restrict__ bs,
                       const float* __restrict__ tW, const float* __restrict__ Wb,
                       int Fin, float* __restrict__ ws_z, float* __restrict__ sbt,
                       float* __restrict__ zb) {
    int w = (blockIdx.x * blockDim.x + threadIdx.x) >> 6;
    int lane = threadIdx.x & 63;
    int total = Fin + 128 + 1;
    if (w >= total) return;
    float s = 0.f;
    if (w < Fin) {
        for (int c = lane; c < 512; c += 64)
            s = fmaf(Ws[(size_t)w * 512 + c], Wb[512 + c] - Wb[1024 + c], s);
    } else if (w < Fin + 128) {
        int m = w - Fin;
        for (int c = lane; c < 512; c += 64)
            s = fmaf(bs[c], tW[(size_t)c * 128 + m], s);
    } else {
        for (int c = lane; c < 512; c += 64)
            s = fmaf(bs[c], Wb[512 + c] - Wb[1024 + c], s);
    }
#pragma unroll
    for (int off = 32; off; off >>= 1) s += __shfl_xor(s, off, 64);
    if (lane == 0) {
        if (w < Fin) ws_z[w] = s;
        else if (w < Fin + 128) sbt[w - Fin] = s;
        else zb[0] = s;
    }
}

// ---------------- CSR build ----------------
__global__ void count_k(const int* __restrict__ dst, const int* __restrict__ em,
                        int E, int* __restrict__ counts) {
    int e = blockIdx.x * blockDim.x + threadIdx.x;
    if (e >= E) return;
    if (em && !em[e]) return;
    atomicAdd(&counts[dst[e]], 1);
}

__global__ void scan_k(const int* __restrict__ counts_in, int* __restrict__ row_start, int N,
                       int* __restrict__ counts_clr) {
    __shared__ int partial[1024];
    const int T = 1024;
    int t = threadIdx.x;
    int per = (N + T - 1) / T;
    int begin = t * per;
    int end = begin + per; if (end > N) end = N;
    int s = 0;
    for (int i = begin; i < end; ++i) s += counts_in[i];
    partial[t] = s;
    __syncthreads();
    for (int st = 1; st < T; st <<= 1) {
        int v = 0;
        if (t >= st) v = partial[t - st];
        __syncthreads();
        if (t >= st) partial[t] += v;
        __syncthreads();
    }
    int run = partial[t] - s;
    for (int i = begin; i < end; ++i) {
        row_start[i] = run; run += counts_in[i]; counts_clr[i] = 0;
    }
    if (t == T - 1) row_start[N] = partial[T - 1];
}

__global__ void scatter_k(const int* __restrict__ src, const int* __restrict__ dst,
                          const int* __restrict__ em, int E,
                          const int* __restrict__ row_start, int* __restrict__ cursor,
                          int* __restrict__ col, int* __restrict__ eid) {
    int e = blockIdx.x * blockDim.x + threadIdx.x;
    if (e >= E) return;
    if (em && !em[e]) return;
    int d = dst[e];
    int p = atomicAdd(&cursor[d], 1);
    int pos = row_start[d] + p;
    col[pos] = src[e];
    eid[pos] = e;
}

// ---------------- all-heads attention on the fused buffer ----------------
// B rows: [S | Q | K | V] (QLD). Wave h handles head h; R nodes per block.
// Q region is overwritten with O in place. zOut4[node*4+h] = O_h . (w1+w3)_h.
template <int R>
__global__ void attn_all_k(float* __restrict__ B,
                           const int* __restrict__ row_start, const int* __restrict__ colb,
                           const int* __restrict__ eidb,
                           const float* __restrict__ ea, const float* __restrict__ We,
                           const float* __restrict__ Wb, float* __restrict__ zOut4) {
    __shared__ float we_s[16 * 512];    // 32 KB
    int tid = threadIdx.x;
    int h = tid >> 6, lane = tid & 63;
    for (int i = tid; i < 16 * 512; i += 256) we_s[i] = We[i];
    __syncthreads();
    int c0 = h * 128 + lane, c1 = c0 + 64;
    float w13a = Wb[c0] + Wb[1024 + c0];
    float w13b = Wb[c1] + Wb[1024 + c1];
    int base = blockIdx.x * R;
    for (int r = 0; r < R; ++r) {
        int node = base + r;
        float* Qr = B + (size_t)node * QLD + 128;
        float q0 = Qr[c0], q1 = Qr[c1];
        float m = -INFINITY, l = 0.f, a0 = 0.f, a1 = 0.f;
        int beg = row_start[node], end = row_start[node + 1];
        for (int j = beg; j < end; ++j) {
            int s = colb[j];
            int e = eidb[j];
            const float4* ea4 = (const float4*)(ea + (size_t)e * 16);
            float ev[16];
            float4* evv = (float4*)ev;
            evv[0] = ea4[0]; evv[1] = ea4[1]; evv[2] = ea4[2]; evv[3] = ea4[3];
            float e0 = 0.f, e1 = 0.f;
#pragma unroll
            for (int d = 0; d < 16; ++d) {
                e0 = fmaf(ev[d], we_s[d * 512 + c0], e0);
                e1 = fmaf(ev[d], we_s[d * 512 + c1], e1);
            }
            const float* Kr = B + (size_t)s * QLD + 640;
            const float* Vr = B + (size_t)s * QLD + 1152;
            float k0 = Kr[c0] + e0;
            float k1 = Kr[c1] + e1;
            float part = q0 * k0 + q1 * k1;
#pragma unroll
            for (int off = 32; off; off >>= 1) part += __shfl_xor(part, off, 64);
            float alpha = part * 0.08838834764831845f;  // 1/sqrt(128)
            float nm = fmaxf(m, alpha);
            float sc = expf(m - nm);      // 0 on first edge (m = -inf)
            float w  = expf(alpha - nm);
            l  = l * sc + w;
            a0 = a0 * sc + w * (Vr[c0] + e0);
            a1 = a1 * sc + w * (Vr[c1] + e1);
            m = nm;
        }
        float inv = 1.f / (l + 1e-16f);
        float o0 = a0 * inv, o1 = a1 * inv;
        Qr[c0] = o0;
        Qr[c1] = o1;
        float zp = o0 * w13a + o1 * w13b;
#pragma unroll
        for (int off = 32; off; off >>= 1) zp += __shfl_xor(zp, off, 64);
        if (lane == 0) zOut4[node * 4 + h] = zp;
    }
}

// ---------------- combine: x_next = relu(beta*(skipT+sbt) + (1-beta)*outT + tb) -------------
// skipT = B[node][0..128), outT = B[node][640..768)
__global__ void combine_k(const float* __restrict__ x, int Fin,
                          const float* __restrict__ ws_z, const float* __restrict__ zb,
                          const float* __restrict__ zOut4, const float* __restrict__ B,
                          const float* __restrict__ sbt, const float* __restrict__ tb,
                          float* __restrict__ xn) {
    __shared__ float red[128];
    int node = blockIdx.x, t = threadIdx.x;  // 128
    red[t] = (t < Fin) ? x[(size_t)node * Fin + t] * ws_z[t] : 0.f;
    __syncthreads();
    for (int st = 64; st; st >>= 1) {
        if (t < st) red[t] += red[t + st];
        __syncthreads();
    }
    float z = zOut4[node * 4] + zOut4[node * 4 + 1] + zOut4[node * 4 + 2] + zOut4[node * 4 + 3]
            + red[0] + zb[0];
    float beta = 1.f / (1.f + expf(-z));
    const float* row = B + (size_t)node * QLD;
    float a = beta * (row[t] + sbt[t]) + (1.f - beta) * row[640 + t] + tb[t];
    xn[(size_t)node * 128 + t] = fmaxf(a, 0.f);
}

// ---------------- batchnorm ----------------
__global__ void bn_stats_k(const float* __restrict__ x, int N, float* __restrict__ stats) {
    int c = threadIdx.x;  // 128
    float s = 0.f, ss = 0.f;
    for (int n = blockIdx.x; n < N; n += gridDim.x) {
        float v = x[(size_t)n * 128 + c];
        s += v; ss += v * v;
    }
    atomicAdd(&stats[c], s);
    atomicAdd(&stats[128 + c], ss);
}

__global__ void bn_apply_k(float* __restrict__ x, int N, const float* __restrict__ stats,
                           const float* __restrict__ g, const float* __restrict__ b) {
    int idx = blockIdx.x * blockDim.x + threadIdx.x;
    if (idx >= N * 128) return;
    int c = idx & 127;
    float m = stats[c] / (float)N;
    float var = fmaxf(stats[128 + c] / (float)N - m * m, 0.f);
    float inv = rsqrtf(var + 1e-5f);
    x[idx] = g[c] * (x[idx] - m) * inv + b[c];
}

// ---------------- pooling ----------------
__global__ void score_k(const float* __restrict__ x, const float* __restrict__ w,
                        float* __restrict__ s, int N) {
    int node = blockIdx.x * 4 + (threadIdx.x >> 6);
    int lane = threadIdx.x & 63;
    float w0 = w[lane], w1 = w[lane + 64];
    float p  = x[(size_t)node * 128 + lane] * w0 + x[(size_t)node * 128 + lane + 64] * w1;
    float nw = w0 * w0 + w1 * w1;
#pragma unroll
    for (int off = 32; off; off >>= 1) {
        p  += __shfl_xor(p, off, 64);
        nw += __shfl_xor(nw, off, 64);
    }
    if (lane == 0) s[node] = p / sqrtf(nw);
}

// one block per graph; thread t = local node t. Stable top-k (lower index wins on ties).
__global__ void topk_k(const float* __restrict__ s, int n, int k,
                       int* __restrict__ keep, int* __restrict__ newid,
                       int* __restrict__ oon, float* __restrict__ tanhs) {
    __shared__ float ls[128];
    __shared__ int lk[128];
    int g = blockIdx.x, t = threadIdx.x;
    int node = g * n + t;
    float val = (t < n) ? s[node] : -INFINITY;
    ls[t] = val;
    __syncthreads();
    int cnt = 0;
    if (t < n) {
        for (int j = 0; j < n; ++j) {
            float vj = ls[j];
            if (vj > val || (vj == val && j < t)) ++cnt;
        }
    }
    int kp = (t < n && cnt < k) ? 1 : 0;
    lk[t] = kp;
    __syncthreads();
    if (t < n) {
        int rank = 0;
        for (int j = 0; j < t; ++j) rank += lk[j];
        keep[node] = kp;
        if (kp) {
            int nid = g * k + rank;
            newid[node] = nid;
            oon[nid] = node;
            tanhs[node] = tanhf(val);
        } else {
            newid[node] = 0;
        }
    }
}

__global__ void gather_k(const float* __restrict__ x, const int* __restrict__ oon,
                         const float* __restrict__ tanhs, float* __restrict__ xo) {
    int nn = blockIdx.x;
    int c = threadIdx.x;  // 128
    int old = oon[nn];
    xo[(size_t)nn * 128 + c] = x[(size_t)old * 128 + c] * tanhs[old];
}

__global__ void readout_k(const float* __restrict__ x, int k, float* __restrict__ rep) {
    int g = blockIdx.x;
    int c = threadIdx.x;  // 128
    float mx = -INFINITY, sm = 0.f;
    for (int r = 0; r < k; ++r) {
        float v = x[(size_t)(g * k + r) * 128 + c];
        mx = fmaxf(mx, v);
        sm += v;
    }
    rep[g * 256 + c] = mx;
    rep[g * 256 + 128 + c] = sm / (float)k;
}

__global__ void remap_k(const int* __restrict__ src, const int* __restrict__ dst,
                        const int* __restrict__ keep, const int* __restrict__ newid,
                        int* __restrict__ src1, int* __restrict__ dst1, int* __restrict__ em1) {
    int e = blockIdx.x * blockDim.x + threadIdx.x;
    if (e >= E_TOT) return;
    int s_ = src[e], d_ = dst[e];
    int m = (keep[s_] && keep[d_]) ? 1 : 0;
    em1[e] = m;
    src1[e] = m ? newid[s_] : 0;
    dst1[e] = m ? newid[d_] : 0;
}

// ---------------- MLP head: one block per graph, fp32 output ----------------
__global__ void head_k(const float* __restrict__ rep0, const float* __restrict__ rep1,
                       const float* __restrict__ W1, const float* __restrict__ b1,
                       const float* __restrict__ W2, const float* __restrict__ b2,
                       const float* __restrict__ W3, const float* __restrict__ b3,
                       float* __restrict__ out) {
    __shared__ float h[256], a1[256], a2[128], red[256];
    int g = blockIdx.x, t = threadIdx.x;  // 256
    h[t] = rep0[g * 256 + t] + rep1[g * 256 + t];
    __syncthreads();
    float acc = b1[t];
    for (int i = 0; i < 256; ++i) acc = fmaf(h[i], W1[i * 256 + t], acc);
    a1[t] = fmaxf(acc, 0.f);
    __syncthreads();
    if (t < 128) {
        float a = b2[t];
        for (int i = 0; i < 256; ++i) a = fmaf(a1[i], W2[i * 128 + t], a);
        a2[t] = fmaxf(a, 0.f);
    }
    __syncthreads();
    red[t] = (t < 128) ? a2[t] * W3[t] : 0.f;
    __syncthreads();
    for (int st = 128; st; st >>= 1) {
        if (t < st) red[t] += red[t + st];
        __syncthreads();
    }
    if (t == 0) out[g] = red[0] + b3[0];
}

// ======================================================================================
extern "C" void kernel_launch(void* const* d_in, const int* in_sizes, int n_in,
                              void* d_out, int out_size, void* d_ws, size_t ws_size,
                              hipStream_t stream) {
    (void)in_sizes; (void)n_in; (void)out_size; (void)ws_size;

    const float* x0    = (const float*)d_in[0];
    const int*   ei    = (const int*)d_in[1];
    const float* ea    = (const float*)d_in[2];
    const float* c1_Wq = (const float*)d_in[3];
    const float* c1_bq = (const float*)d_in[4];
    const float* c1_Wk = (const float*)d_in[5];
    const float* c1_bk = (const float*)d_in[6];
    const float* c1_Wv = (const float*)d_in[7];
    const float* c1_bv = (const float*)d_in[8];
    const float* c1_We = (const float*)d_in[9];
    const float* c1_Ws = (const float*)d_in[10];
    const float* c1_bs = (const float*)d_in[11];
    const float* c1_Wb = (const float*)d_in[12];
    const float* t1_W  = (const float*)d_in[13];
    const float* t1_b  = (const float*)d_in[14];
    const float* bn1_g = (const float*)d_in[15];
    const float* bn1_b = (const float*)d_in[16];
    const float* cl_Wq = (const float*)d_in[17];
    const float* cl_bq = (const float*)d_in[18];
    const float* cl_Wk = (const float*)d_in[19];
    const float* cl_bk = (const float*)d_in[20];
    const float* cl_Wv = (const float*)d_in[21];
    const float* cl_bv = (const float*)d_in[22];
    const float* cl_We = (const float*)d_in[23];
    const float* cl_Ws = (const float*)d_in[24];
    const float* cl_bs = (const float*)d_in[25];
    const float* cl_Wb = (const float*)d_in[26];
    const float* tl_W  = (const float*)d_in[27];
    const float* tl_b  = (const float*)d_in[28];
    const float* bnl_g = (const float*)d_in[29];
    const float* bnl_b = (const float*)d_in[30];
    const float* pool_w= (const float*)d_in[31];
    const float* l1_W  = (const float*)d_in[32];
    const float* l1_b  = (const float*)d_in[33];
    const float* l2_W  = (const float*)d_in[34];
    const float* l2_b  = (const float*)d_in[35];
    const float* l3_W  = (const float*)d_in[36];
    const float* l3_b  = (const float*)d_in[37];
    float* out = (float*)d_out;

    // -------- workspace layout (~129 MB) --------
    char* base = (char*)d_ws;
    size_t off = 0;
    auto alloc = [&](size_t bytes) -> void* {
        void* p = base + off;
        off += (bytes + 255) & ~(size_t)255;
        return p;
    };
    float* QB   = (float*)alloc((size_t)16384 * QLD * 4);   // fused S|Q/O|K/outT|V  (109 MB)
    float* xA   = (float*)alloc((size_t)16384 * 128 * 4);   // layer outputs / xp alias
    float* xB   = (float*)alloc((size_t)16384 * 128 * 4);
    float* xp2  = (float*)alloc((size_t)4096 * 128 * 4);
    float* zOut4= (float*)alloc((size_t)16384 * 4 * 4);
    float* Wst  = (float*)alloc(128 * 128 * 4);
    float* ws_z = (float*)alloc(128 * 4);
    float* sbt  = (float*)alloc(128 * 4);
    float* zb   = (float*)alloc(4 * 4);
    float* stats  = (float*)alloc(256 * 4);
    float* scores = (float*)alloc(16384 * 4);
    float* tanhs  = (float*)alloc(16384 * 4);
    float* rep0   = (float*)alloc(128 * 256 * 4);
    float* rep1   = (float*)alloc(128 * 256 * 4);
    int* row_start = (int*)alloc(16385 * 4);
    int* counts    = (int*)alloc(16384 * 4);
    int* colb      = (int*)alloc(E_TOT * 4);
    int* eidb      = (int*)alloc(E_TOT * 4);
    int* src1      = (int*)alloc(E_TOT * 4);
    int* dst1      = (int*)alloc(E_TOT * 4);
    int* em1       = (int*)alloc(E_TOT * 4);
    int* keep      = (int*)alloc(16384 * 4);
    int* newid     = (int*)alloc(16384 * 4);
    int* oon       = (int*)alloc(8192 * 4);
    float* xp = xA;   // alias: xA dead once loop-0's combine has consumed it

    auto build_csr = [&](const int* srcp, const int* dstp, const int* emp, int N) {
        hipMemsetAsync(counts, 0, (size_t)N * 4, stream);
        count_k<<<E_TOT / 256, 256, 0, stream>>>(dstp, emp, E_TOT, counts);
        scan_k<<<1, 1024, 0, stream>>>(counts, row_start, N, counts);
        scatter_k<<<E_TOT / 256, 256, 0, stream>>>(srcp, dstp, emp, E_TOT, row_start, counts, colb, eidb);
    };

    // Full tconv + t-layer(+bias+relu): xn = relu(gated @ tW + tb)
    auto tconv = [&](const float* xin, int N, int Fin,
                     const float* Wq, const float* bq, const float* Wk, const float* bk,
                     const float* Wv, const float* bv, const float* We,
                     const float* Ws, const float* bs, const float* Wb,
                     const float* tW, const float* tb, float* xn) {
        compose_k<<<(Fin * 128 + 3) / 4, 256, 0, stream>>>(Ws, tW, Fin, Wst);
        vecs_k<<<(Fin + 128 + 1 + 3) / 4, 256, 0, stream>>>(Ws, bs, tW, Wb, Fin, ws_z, sbt, zb);
        int kcs = (Fin == 64) ? 6 : 7;
        qkvs_gemm<<<dim3(7, N / 16), 128, 0, stream>>>(xin, Fin, Fin, kcs,
                                                       Wst, Wq, bq, Wk, bk, Wv, bv, QB);
        attn_all_k<8><<<N / 8, 256, 0, stream>>>(QB, row_start, colb, eidb, ea, We, Wb, zOut4);
        out_gemm<<<N / 32, 128, 0, stream>>>(QB + 128, QLD, tW, QB + 640, QLD);
        combine_k<<<N, 128, 0, stream>>>(xin, Fin, ws_z, zb, zOut4, QB, sbt, tb, xn);
    };

    auto bn = [&](float* x, int N, const float* g, const float* b) {
        hipMemsetAsync(stats, 0, 256 * 4, stream);
        bn_stats_k<<<128, 128, 0, stream>>>(x, N, stats);
        bn_apply_k<<<(N * 128 + 255) / 256, 256, 0, stream>>>(x, N, stats, g, b);
    };

    // ---- CSR over original edges (used by layer 1 and loop layer 0) ----
    build_csr(ei, ei + E_TOT, nullptr, 16384);

    // ---- layer 1: tconv(Fin=64) + t1 + bn1 ----
    tconv(x0, 16384, 64, c1_Wq, c1_bq, c1_Wk, c1_bk, c1_Wv, c1_bv, c1_We,
          c1_Ws, c1_bs, c1_Wb, t1_W, t1_b, xA);
    bn(xA, 16384, bn1_g, bn1_b);

    // ---- loop layer 0 (Fin=128, N=16384) ----
    tconv(xA, 16384, 128, cl_Wq, cl_bq, cl_Wk, cl_bk, cl_Wv, cl_bv, cl_We,
          cl_Ws, cl_bs, cl_Wb, tl_W, tl_b, xB);
    bn(xB, 16384, bnl_g, bnl_b);

    // ---- pool 0 (n=128 -> k=64) ----
    score_k<<<16384 / 4, 256, 0, stream>>>(xB, pool_w, scores, 16384);
    topk_k<<<B_G, 128, 0, stream>>>(scores, 128, 64, keep, newid, oon, tanhs);
    gather_k<<<8192, 128, 0, stream>>>(xB, oon, tanhs, xp);
    readout_k<<<B_G, 128, 0, stream>>>(xp, 64, rep0);
    remap_k<<<E_TOT / 256, 256, 0, stream>>>(ei, ei + E_TOT, keep, newid, src1, dst1, em1);

    // ---- CSR over remapped edges (8192 nodes) ----
    build_csr(src1, dst1, em1, 8192);

    // ---- loop layer 1 (Fin=128, N=8192) ----
    tconv(xp, 8192, 128,
          cl_Wq + 65536, cl_bq + 512, cl_Wk + 65536, cl_bk + 512,
          cl_Wv + 65536, cl_bv + 512, cl_We + 8192,
          cl_Ws + 65536, cl_bs + 512, cl_Wb + 1536,
          tl_W + 65536, tl_b + 128, xB);
    bn(xB, 8192, bnl_g + 128, bnl_b + 128);

    // ---- pool 1 (n=64 -> k=32) ----
    score_k<<<8192 / 4, 256, 0, stream>>>(xB, pool_w + 128, scores, 8192);
    topk_k<<<B_G, 128, 0, stream>>>(scores, 64, 32, keep, newid, oon, tanhs);
    gather_k<<<4096, 128, 0, stream>>>(xB, oon, tanhs, xp2);
    readout_k<<<B_G, 128, 0, stream>>>(xp2, 32, rep1);

    // ---- MLP head (fp32 out) ----
    head_k<<<B_G, 256, 0, stream>>>(rep0, rep1, l1_W, l1_b, l2_W, l2_b, l3_W, l3_b, out);
}

// Round 7
// 992.306 us; speedup vs baseline: 1.8145x; 1.1460x over previous
//
#include <hip/hip_runtime.h>
#include <math.h>

#define E_TOT 65536
#define B_G   128
#define QLD   1664   // fused buffer row: [S(128) | Q/O(512) | K/outT0(512) | V/outT1(512)]

// ---------------- fused S/Q/K/V GEMM, 4 cols/thread ----------------
// grid (4, N/16), block 128. Blocks 0-2: 512 cols (4/thread); block 3: 128 cols (1/thread).
__global__ __launch_bounds__(128) void qkvs_gemm(
        const float* __restrict__ X, int ldX, int K, int kcs,
        const float* __restrict__ Wst,
        const float* __restrict__ Wq, const float* __restrict__ bq,
        const float* __restrict__ Wk, const float* __restrict__ bk,
        const float* __restrict__ Wv, const float* __restrict__ bv,
        float* __restrict__ out) {
    const int PAD = 20;
    __shared__ __align__(16) float xs[128 * PAD];
    int tid = threadIdx.x;
    int n0 = blockIdx.y * 16;
    int KC = 1 << kcs, kcm = KC - 1;
    int base = blockIdx.x * 512;
    const int nc = (blockIdx.x < 3) ? 4 : 1;

    const float* w[4];
    int ld[4], col[4];
    float acc[4][16];
#pragma unroll
    for (int j = 0; j < 4; ++j) {
        col[j] = base + tid + j * 128;
        int c = (j < nc) ? col[j] : 0;
        float bj = 0.f;
        if (c < 128)       { w[j] = Wst + c;         ld[j] = 128; }
        else if (c < 640)  { w[j] = Wq + (c - 128);  ld[j] = 512; bj = bq[c - 128]; }
        else if (c < 1152) { w[j] = Wk + (c - 640);  ld[j] = 512; bj = bk[c - 640]; }
        else               { w[j] = Wv + (c - 1152); ld[j] = 512; bj = bv[c - 1152]; }
#pragma unroll
        for (int r = 0; r < 16; ++r) acc[j][r] = bj;
    }

    for (int k0 = 0; k0 < K; k0 += KC) {
        for (int i = tid; i < 16 * KC; i += 128) {
            int kk = i & kcm, r = i >> kcs;
            xs[kk * PAD + r] = X[(size_t)(n0 + r) * ldX + k0 + kk];
        }
        __syncthreads();
        if (nc == 4) {
#pragma unroll 2
            for (int kk = 0; kk < KC; ++kk) {
                const float* xr = xs + kk * PAD;
                float xv[16];
                float4* xvv = (float4*)xv;
                xvv[0] = *(const float4*)(xr);
                xvv[1] = *(const float4*)(xr + 4);
                xvv[2] = *(const float4*)(xr + 8);
                xvv[3] = *(const float4*)(xr + 12);
                float a0 = *w[0]; w[0] += ld[0];
                float a1 = *w[1]; w[1] += ld[1];
                float a2 = *w[2]; w[2] += ld[2];
                float a3 = *w[3]; w[3] += ld[3];
#pragma unroll
                for (int r = 0; r < 16; ++r) {
                    acc[0][r] = fmaf(xv[r], a0, acc[0][r]);
                    acc[1][r] = fmaf(xv[r], a1, acc[1][r]);
                    acc[2][r] = fmaf(xv[r], a2, acc[2][r]);
                    acc[3][r] = fmaf(xv[r], a3, acc[3][r]);
                }
            }
        } else {
#pragma unroll 4
            for (int kk = 0; kk < KC; ++kk) {
                const float* xr = xs + kk * PAD;
                float xv[16];
                float4* xvv = (float4*)xv;
                xvv[0] = *(const float4*)(xr);
                xvv[1] = *(const float4*)(xr + 4);
                xvv[2] = *(const float4*)(xr + 8);
                xvv[3] = *(const float4*)(xr + 12);
                float a0 = *w[0]; w[0] += ld[0];
#pragma unroll
                for (int r = 0; r < 16; ++r) acc[0][r] = fmaf(xv[r], a0, acc[0][r]);
            }
        }
        __syncthreads();
    }
#pragma unroll
    for (int j = 0; j < 4; ++j) {
        if (j >= nc) break;
#pragma unroll
        for (int r = 0; r < 16; ++r)
            out[(size_t)(n0 + r) * QLD + col[j]] = acc[j][r];
    }
}

// ---------------- outT GEMM: partials of O @ tW into K (p=0) and V (p=1) regions -------------
// grid (N/32, 2), block 64 (1 wave), 2 cols/thread, K-half 256 per y-block.
__global__ __launch_bounds__(64) void out_gemm(float* __restrict__ QB,
                                               const float* __restrict__ W) {
    const int ROWS = 32, PAD = 36, KC = 128;
    __shared__ __align__(16) float xs[KC * PAD];
    int tid = threadIdx.x;        // 64
    int n0 = blockIdx.x * ROWS;
    int kb = blockIdx.y * 256;
    int oo = blockIdx.y ? 1152 : 640;
    float acc0[ROWS], acc1[ROWS];
#pragma unroll
    for (int r = 0; r < ROWS; ++r) { acc0[r] = 0.f; acc1[r] = 0.f; }
    const float* wp0 = W + (size_t)kb * 128 + tid;
    const float* wp1 = wp0 + 64;
    for (int k0 = 0; k0 < 256; k0 += KC) {
        for (int i = tid; i < ROWS * KC; i += 64) {
            int kk = i & 127, r = i >> 7;
            xs[kk * PAD + r] = QB[(size_t)(n0 + r) * QLD + 128 + kb + k0 + kk];
        }
        __syncthreads();
#pragma unroll 2
        for (int kk = 0; kk < KC; ++kk) {
            const float* xr = xs + kk * PAD;
            float xv[ROWS];
            float4* xvv = (float4*)xv;
#pragma unroll
            for (int q = 0; q < 8; ++q) xvv[q] = *(const float4*)(xr + 4 * q);
            float w0 = *wp0; wp0 += 128;
            float w1 = *wp1; wp1 += 128;
#pragma unroll
            for (int r = 0; r < ROWS; ++r) {
                acc0[r] = fmaf(xv[r], w0, acc0[r]);
                acc1[r] = fmaf(xv[r], w1, acc1[r]);
            }
        }
        __syncthreads();
    }
#pragma unroll
    for (int r = 0; r < ROWS; ++r) {
        QB[(size_t)(n0 + r) * QLD + oo + tid]      = acc0[r];
        QB[(size_t)(n0 + r) * QLD + oo + tid + 64] = acc1[r];
    }
}

// ---------------- fused per-layer weight prep: Wst + ws_z + sbt + zb (warp per output) -------
__global__ void prep_k(const float* __restrict__ Ws, const float* __restrict__ bs,
                       const float* __restrict__ tW, const float* __restrict__ Wb,
                       int Fin, float* __restrict__ Wst, float* __restrict__ ws_z,
                       float* __restrict__ sbt, float* __restrict__ zb) {
    int w = (blockIdx.x * blockDim.x + threadIdx.x) >> 6;
    int lane = threadIdx.x & 63;
    int nW = Fin * 128;
    int total = nW + Fin + 128 + 1;
    if (w >= total) return;
    float s = 0.f;
    if (w < nW) {
        int f = w >> 7, m = w & 127;
        for (int c = lane; c < 512; c += 64)
            s = fmaf(Ws[(size_t)f * 512 + c], tW[(size_t)c * 128 + m], s);
    } else if (w < nW + Fin) {
        int f = w - nW;
        for (int c = lane; c < 512; c += 64)
            s = fmaf(Ws[(size_t)f * 512 + c], Wb[512 + c] - Wb[1024 + c], s);
    } else if (w < nW + Fin + 128) {
        int m = w - nW - Fin;
        for (int c = lane; c < 512; c += 64)
            s = fmaf(bs[c], tW[(size_t)c * 128 + m], s);
    } else {
        for (int c = lane; c < 512; c += 64)
            s = fmaf(bs[c], Wb[512 + c] - Wb[1024 + c], s);
    }
#pragma unroll
    for (int off = 32; off; off >>= 1) s += __shfl_xor(s, off, 64);
    if (lane == 0) {
        if (w < nW) Wst[w] = s;
        else if (w < nW + Fin) ws_z[w - nW] = s;
        else if (w < nW + Fin + 128) sbt[w - nW - Fin] = s;
        else zb[0] = s;
    }
}

// ---------------- per-graph CSR build (edges of graph g are [g*512,(g+1)*512)) --------------
__global__ __launch_bounds__(128) void csr_graph_k(const int* __restrict__ src,
                                                   const int* __restrict__ dst,
                                                   int* __restrict__ row_start,
                                                   int* __restrict__ row_end,
                                                   int* __restrict__ colb,
                                                   int* __restrict__ eidb) {
    __shared__ int cnt[128], pref[128], cur[128];
    int g = blockIdx.x, t = threadIdx.x;
    cnt[t] = 0;
    __syncthreads();
    int e0 = g * 512, nb = g * 128;
    int dl[4], sl[4];
#pragma unroll
    for (int i = 0; i < 4; ++i) {
        int e = e0 + t + i * 128;
        dl[i] = dst[e] - nb;
        sl[i] = src[e];
        atomicAdd(&cnt[dl[i]], 1);
    }
    __syncthreads();
    pref[t] = cnt[t];
    __syncthreads();
    for (int st = 1; st < 128; st <<= 1) {
        int v = (t >= st) ? pref[t - st] : 0;
        __syncthreads();
        pref[t] += v;
        __syncthreads();
    }
    int ex = pref[t] - cnt[t];
    row_start[nb + t] = e0 + ex;
    row_end[nb + t]   = e0 + pref[t];
    cur[t] = ex;
    __syncthreads();
#pragma unroll
    for (int i = 0; i < 4; ++i) {
        int pos = atomicAdd(&cur[dl[i]], 1);
        colb[e0 + pos] = sl[i];
        eidb[e0 + pos] = e0 + t + i * 128;
    }
}

// ---------------- all-heads attention on the fused buffer ----------------
template <int R>
__global__ void attn_all_k(float* __restrict__ B,
                           const int* __restrict__ row_start, const int* __restrict__ row_end,
                           const int* __restrict__ colb, const int* __restrict__ eidb,
                           const float* __restrict__ ea, const float* __restrict__ We,
                           const float* __restrict__ Wb, float* __restrict__ zOut4) {
    __shared__ float we_s[16 * 512];    // 32 KB
    int tid = threadIdx.x;
    int h = tid >> 6, lane = tid & 63;
    for (int i = tid; i < 16 * 512; i += 256) we_s[i] = We[i];
    __syncthreads();
    int c0 = h * 128 + lane, c1 = c0 + 64;
    float w13a = Wb[c0] + Wb[1024 + c0];
    float w13b = Wb[c1] + Wb[1024 + c1];
    int base = blockIdx.x * R;
    for (int r = 0; r < R; ++r) {
        int node = base + r;
        float* Qr = B + (size_t)node * QLD + 128;
        float q0 = Qr[c0], q1 = Qr[c1];
        float m = -INFINITY, l = 0.f, a0 = 0.f, a1 = 0.f;
        int beg = row_start[node], end = row_end[node];
        for (int j = beg; j < end; ++j) {
            int s = colb[j];
            int e = eidb[j];
            const float4* ea4 = (const float4*)(ea + (size_t)e * 16);
            float ev[16];
            float4* evv = (float4*)ev;
            evv[0] = ea4[0]; evv[1] = ea4[1]; evv[2] = ea4[2]; evv[3] = ea4[3];
            float e0 = 0.f, e1 = 0.f;
#pragma unroll
            for (int d = 0; d < 16; ++d) {
                e0 = fmaf(ev[d], we_s[d * 512 + c0], e0);
                e1 = fmaf(ev[d], we_s[d * 512 + c1], e1);
            }
            const float* Kr = B + (size_t)s * QLD + 640;
            const float* Vr = B + (size_t)s * QLD + 1152;
            float k0 = Kr[c0] + e0;
            float k1 = Kr[c1] + e1;
            float part = q0 * k0 + q1 * k1;
#pragma unroll
            for (int off = 32; off; off >>= 1) part += __shfl_xor(part, off, 64);
            float alpha = part * 0.08838834764831845f;  // 1/sqrt(128)
            float nm = fmaxf(m, alpha);
            float sc = expf(m - nm);      // 0 on first edge (m = -inf)
            float w  = expf(alpha - nm);
            l  = l * sc + w;
            a0 = a0 * sc + w * (Vr[c0] + e0);
            a1 = a1 * sc + w * (Vr[c1] + e1);
            m = nm;
        }
        float inv = 1.f / (l + 1e-16f);
        float o0 = a0 * inv, o1 = a1 * inv;
        Qr[c0] = o0;
        Qr[c1] = o1;
        float zp = o0 * w13a + o1 * w13b;
#pragma unroll
        for (int off = 32; off; off >>= 1) zp += __shfl_xor(zp, off, 64);
        if (lane == 0) zOut4[node * 4 + h] = zp;
    }
}

// ---------------- combine: x_next = relu(beta*(skipT+sbt) + (1-beta)*outT + tb) -------------
__global__ void combine_k(const float* __restrict__ x, int Fin,
                          const float* __restrict__ ws_z, const float* __restrict__ zb,
                          const float* __restrict__ zOut4, const float* __restrict__ B,
                          const float* __restrict__ sbt, const float* __restrict__ tb,
                          float* __restrict__ xn) {
    __shared__ float red[128];
    int node = blockIdx.x, t = threadIdx.x;  // 128
    red[t] = (t < Fin) ? x[(size_t)node * Fin + t] * ws_z[t] : 0.f;
    __syncthreads();
    for (int st = 64; st; st >>= 1) {
        if (t < st) red[t] += red[t + st];
        __syncthreads();
    }
    float z = zOut4[node * 4] + zOut4[node * 4 + 1] + zOut4[node * 4 + 2] + zOut4[node * 4 + 3]
            + red[0] + zb[0];
    float beta = 1.f / (1.f + expf(-z));
    const float* row = B + (size_t)node * QLD;
    float outT = row[640 + t] + row[1152 + t];
    float a = beta * (row[t] + sbt[t]) + (1.f - beta) * outT + tb[t];
    xn[(size_t)node * 128 + t] = fmaxf(a, 0.f);
}

// ---------------- batchnorm ----------------
__global__ void bn_stats_k(const float* __restrict__ x, int N, float* __restrict__ stats) {
    int c = threadIdx.x;  // 128
    float s = 0.f, ss = 0.f;
    for (int n = blockIdx.x; n < N; n += gridDim.x) {
        float v = x[(size_t)n * 128 + c];
        s += v; ss += v * v;
    }
    atomicAdd(&stats[c], s);
    atomicAdd(&stats[128 + c], ss);
}

__global__ void bn_apply_k(float* __restrict__ x, int N, const float* __restrict__ stats,
                           const float* __restrict__ g, const float* __restrict__ b) {
    int idx = blockIdx.x * blockDim.x + threadIdx.x;
    if (idx >= N * 128) return;
    int c = idx & 127;
    float m = stats[c] / (float)N;
    float var = fmaxf(stats[128 + c] / (float)N - m * m, 0.f);
    float inv = rsqrtf(var + 1e-5f);
    x[idx] = g[c] * (x[idx] - m) * inv + b[c];
}

// bn apply + pooling score in one pass (wave = node). grid N/4, block 256.
__global__ void bn_apply_score_k(float* __restrict__ x, int N, const float* __restrict__ stats,
                                 const float* __restrict__ g, const float* __restrict__ b,
                                 const float* __restrict__ w, float* __restrict__ s) {
    int node = blockIdx.x * 4 + (threadIdx.x >> 6);
    int lane = threadIdx.x & 63;
    int c0 = lane, c1 = lane + 64;
    float m0 = stats[c0] / (float)N;
    float v0 = fmaxf(stats[128 + c0] / (float)N - m0 * m0, 0.f);
    float m1 = stats[c1] / (float)N;
    float v1 = fmaxf(stats[128 + c1] / (float)N - m1 * m1, 0.f);
    float* row = x + (size_t)node * 128;
    float x0 = g[c0] * (row[c0] - m0) * rsqrtf(v0 + 1e-5f) + b[c0];
    float x1 = g[c1] * (row[c1] - m1) * rsqrtf(v1 + 1e-5f) + b[c1];
    row[c0] = x0;
    row[c1] = x1;
    float w0 = w[c0], w1 = w[c1];
    float p  = x0 * w0 + x1 * w1;
    float nw = w0 * w0 + w1 * w1;
#pragma unroll
    for (int off = 32; off; off >>= 1) {
        p  += __shfl_xor(p, off, 64);
        nw += __shfl_xor(nw, off, 64);
    }
    if (lane == 0) s[node] = p / sqrtf(nw);
}

// ---------------- pool0: topk + gather + readout + per-graph CSR rebuild --------------------
// block = 128 threads, one graph. n=128 -> k=64.
__global__ __launch_bounds__(128) void topk_pool0_k(
        const float* __restrict__ sc, const float* __restrict__ x,
        const int* __restrict__ src, const int* __restrict__ dst,
        float* __restrict__ xp, float* __restrict__ rep,
        int* __restrict__ row_start, int* __restrict__ row_end,
        int* __restrict__ colb, int* __restrict__ eidb) {
    __shared__ float ls[128], th[64];
    __shared__ int lk[128], rk[128], oon[64];
    __shared__ int cnt[64], pref[64], cur[64];
    int g = blockIdx.x, t = threadIdx.x;
    float val = sc[g * 128 + t];
    ls[t] = val;
    __syncthreads();
    int c = 0;
    for (int j = 0; j < 128; ++j) {
        float vj = ls[j];
        c += (vj > val || (vj == val && j < t)) ? 1 : 0;
    }
    int kp = (c < 64) ? 1 : 0;
    lk[t] = kp;
    __syncthreads();
    int r = 0;
    for (int j = 0; j < t; ++j) r += lk[j];
    rk[t] = r;
    if (kp) { oon[r] = t; th[r] = tanhf(val); }
    __syncthreads();
    // gather + readout (t = channel)
    float mx = -INFINITY, sm = 0.f;
    for (int rr = 0; rr < 64; ++rr) {
        float v = x[(size_t)(g * 128 + oon[rr]) * 128 + t] * th[rr];
        xp[(size_t)(g * 64 + rr) * 128 + t] = v;
        mx = fmaxf(mx, v);
        sm += v;
    }
    rep[g * 256 + t] = mx;
    rep[g * 256 + 128 + t] = sm * (1.f / 64.f);
    // CSR rebuild over kept edges
    if (t < 64) cnt[t] = 0;
    __syncthreads();
    int e0 = g * 512, nb = g * 128;
    int keepE[4], dr[4], sr[4];
#pragma unroll
    for (int i = 0; i < 4; ++i) {
        int e = e0 + t + i * 128;
        int s_ = src[e] - nb, d_ = dst[e] - nb;
        int ke = lk[s_] && lk[d_];
        keepE[i] = ke;
        dr[i] = rk[d_];
        sr[i] = rk[s_];
        if (ke) atomicAdd(&cnt[dr[i]], 1);
    }
    __syncthreads();
    if (t < 64) pref[t] = cnt[t];
    __syncthreads();
    for (int st = 1; st < 64; st <<= 1) {
        int v = (t < 64 && t >= st) ? pref[t - st] : 0;
        __syncthreads();
        if (t < 64) pref[t] += v;
        __syncthreads();
    }
    if (t < 64) {
        int ex = pref[t] - cnt[t];
        row_start[g * 64 + t] = e0 + ex;
        row_end[g * 64 + t]   = e0 + pref[t];
        cur[t] = ex;
    }
    __syncthreads();
#pragma unroll
    for (int i = 0; i < 4; ++i) {
        if (keepE[i]) {
            int pos = atomicAdd(&cur[dr[i]], 1);
            colb[e0 + pos] = g * 64 + sr[i];
            eidb[e0 + pos] = e0 + t + i * 128;
        }
    }
}

// ---------------- pool1: topk + readout only. n=64 -> k=32. block 128. ----------------------
__global__ __launch_bounds__(128) void topk_pool1_k(
        const float* __restrict__ sc, const float* __restrict__ x,
        float* __restrict__ rep) {
    __shared__ float ls[64], th[32];
    __shared__ int lk[64], oon[32];
    int g = blockIdx.x, t = threadIdx.x;
    float val = 0.f;
    if (t < 64) { val = sc[g * 64 + t]; ls[t] = val; }
    __syncthreads();
    if (t < 64) {
        int c = 0;
        for (int j = 0; j < 64; ++j) {
            float vj = ls[j];
            c += (vj > val || (vj == val && j < t)) ? 1 : 0;
        }
        int kp = (c < 32) ? 1 : 0;
        lk[t] = kp;
    }
    __syncthreads();
    if (t < 64 && lk[t]) {
        int r = 0;
        for (int j = 0; j < t; ++j) r += lk[j];
        oon[r] = t;
        th[r] = tanhf(val);
    }
    __syncthreads();
    float mx = -INFINITY, sm = 0.f;
    for (int rr = 0; rr < 32; ++rr) {
        float v = x[(size_t)(g * 64 + oon[rr]) * 128 + t] * th[rr];
        mx = fmaxf(mx, v);
        sm += v;
    }
    rep[g * 256 + t] = mx;
    rep[g * 256 + 128 + t] = sm * (1.f / 32.f);
}

// ---------------- MLP head: one block per graph, fp32 output ----------------
__global__ void head_k(const float* __restrict__ rep0, const float* __restrict__ rep1,
                       const float* __restrict__ W1, const float* __restrict__ b1,
                       const float* __restrict__ W2, const float* __restrict__ b2,
                       const float* __restrict__ W3, const float* __restrict__ b3,
                       float* __restrict__ out) {
    __shared__ float h[256], a1[256], a2[128], red[256];
    int g = blockIdx.x, t = threadIdx.x;  // 256
    h[t] = rep0[g * 256 + t] + rep1[g * 256 + t];
    __syncthreads();
    float acc = b1[t];
    for (int i = 0; i < 256; ++i) acc = fmaf(h[i], W1[i * 256 + t], acc);
    a1[t] = fmaxf(acc, 0.f);
    __syncthreads();
    if (t < 128) {
        float a = b2[t];
        for (int i = 0; i < 256; ++i) a = fmaf(a1[i], W2[i * 128 + t], a);
        a2[t] = fmaxf(a, 0.f);
    }
    __syncthreads();
    red[t] = (t < 128) ? a2[t] * W3[t] : 0.f;
    __syncthreads();
    for (int st = 128; st; st >>= 1) {
        if (t < st) red[t] += red[t + st];
        __syncthreads();
    }
    if (t == 0) out[g] = red[0] + b3[0];
}

// ======================================================================================
extern "C" void kernel_launch(void* const* d_in, const int* in_sizes, int n_in,
                              void* d_out, int out_size, void* d_ws, size_t ws_size,
                              hipStream_t stream) {
    (void)in_sizes; (void)n_in; (void)out_size; (void)ws_size;

    const float* x0    = (const float*)d_in[0];
    const int*   ei    = (const int*)d_in[1];
    const float* ea    = (const float*)d_in[2];
    const float* c1_Wq = (const float*)d_in[3];
    const float* c1_bq = (const float*)d_in[4];
    const float* c1_Wk = (const float*)d_in[5];
    const float* c1_bk = (const float*)d_in[6];
    const float* c1_Wv = (const float*)d_in[7];
    const float* c1_bv = (const float*)d_in[8];
    const float* c1_We = (const float*)d_in[9];
    const float* c1_Ws = (const float*)d_in[10];
    const float* c1_bs = (const float*)d_in[11];
    const float* c1_Wb = (const float*)d_in[12];
    const float* t1_W  = (const float*)d_in[13];
    const float* t1_b  = (const float*)d_in[14];
    const float* bn1_g = (const float*)d_in[15];
    const float* bn1_b = (const float*)d_in[16];
    const float* cl_Wq = (const float*)d_in[17];
    const float* cl_bq = (const float*)d_in[18];
    const float* cl_Wk = (const float*)d_in[19];
    const float* cl_bk = (const float*)d_in[20];
    const float* cl_Wv = (const float*)d_in[21];
    const float* cl_bv = (const float*)d_in[22];
    const float* cl_We = (const float*)d_in[23];
    const float* cl_Ws = (const float*)d_in[24];
    const float* cl_bs = (const float*)d_in[25];
    const float* cl_Wb = (const float*)d_in[26];
    const float* tl_W  = (const float*)d_in[27];
    const float* tl_b  = (const float*)d_in[28];
    const float* bnl_g = (const float*)d_in[29];
    const float* bnl_b = (const float*)d_in[30];
    const float* pool_w= (const float*)d_in[31];
    const float* l1_W  = (const float*)d_in[32];
    const float* l1_b  = (const float*)d_in[33];
    const float* l2_W  = (const float*)d_in[34];
    const float* l2_b  = (const float*)d_in[35];
    const float* l3_W  = (const float*)d_in[36];
    const float* l3_b  = (const float*)d_in[37];
    float* out = (float*)d_out;

    // -------- workspace layout (~127 MB) --------
    char* base = (char*)d_ws;
    size_t off = 0;
    auto alloc = [&](size_t bytes) -> void* {
        void* p = base + off;
        off += (bytes + 255) & ~(size_t)255;
        return p;
    };
    float* QB   = (float*)alloc((size_t)16384 * QLD * 4);   // 109 MB
    float* xA   = (float*)alloc((size_t)16384 * 128 * 4);
    float* xB   = (float*)alloc((size_t)16384 * 128 * 4);
    float* zOut4= (float*)alloc((size_t)16384 * 4 * 4);
    float* Wst  = (float*)alloc(128 * 128 * 4);
    float* ws_z = (float*)alloc(128 * 4);
    float* sbt  = (float*)alloc(128 * 4);
    float* zb   = (float*)alloc(4 * 4);
    float* stats  = (float*)alloc(256 * 4);
    float* scores = (float*)alloc(16384 * 4);
    float* rep0   = (float*)alloc(128 * 256 * 4);
    float* rep1   = (float*)alloc(128 * 256 * 4);
    int* row_start = (int*)alloc(16384 * 4);
    int* row_end   = (int*)alloc(16384 * 4);
    int* colb      = (int*)alloc(E_TOT * 4);
    int* eidb      = (int*)alloc(E_TOT * 4);
    float* xp = xA;  // alias: xA dead once loop-0's combine has consumed it

    // Full tconv + t-layer(+bias+relu): xn = relu(gated @ tW + tb)
    auto tconv = [&](const float* xin, int N, int Fin,
                     const float* Wq, const float* bq, const float* Wk, const float* bk,
                     const float* Wv, const float* bv, const float* We,
                     const float* Ws, const float* bs, const float* Wb,
                     const float* tW, const float* tb, float* xn) {
        int totW = Fin * 128 + Fin + 128 + 1;
        prep_k<<<(totW + 3) / 4, 256, 0, stream>>>(Ws, bs, tW, Wb, Fin, Wst, ws_z, sbt, zb);
        int kcs = (Fin == 64) ? 6 : 7;
        qkvs_gemm<<<dim3(4, N / 16), 128, 0, stream>>>(xin, Fin, Fin, kcs,
                                                       Wst, Wq, bq, Wk, bk, Wv, bv, QB);
        attn_all_k<8><<<N / 8, 256, 0, stream>>>(QB, row_start, row_end, colb, eidb,
                                                 ea, We, Wb, zOut4);
        out_gemm<<<dim3(N / 32, 2), 64, 0, stream>>>(QB, tW);
        combine_k<<<N, 128, 0, stream>>>(xin, Fin, ws_z, zb, zOut4, QB, sbt, tb, xn);
    };

    // ---- CSR over original edges (per-graph, one kernel) ----
    csr_graph_k<<<B_G, 128, 0, stream>>>(ei, ei + E_TOT, row_start, row_end, colb, eidb);

    // ---- layer 1: tconv(Fin=64) + t1 + bn1 ----
    tconv(x0, 16384, 64, c1_Wq, c1_bq, c1_Wk, c1_bk, c1_Wv, c1_bv, c1_We,
          c1_Ws, c1_bs, c1_Wb, t1_W, t1_b, xA);
    hipMemsetAsync(stats, 0, 256 * 4, stream);
    bn_stats_k<<<128, 128, 0, stream>>>(xA, 16384, stats);
    bn_apply_k<<<(16384 * 128 + 255) / 256, 256, 0, stream>>>(xA, 16384, stats, bn1_g, bn1_b);

    // ---- loop layer 0 (Fin=128, N=16384) ----
    tconv(xA, 16384, 128, cl_Wq, cl_bq, cl_Wk, cl_bk, cl_Wv, cl_bv, cl_We,
          cl_Ws, cl_bs, cl_Wb, tl_W, tl_b, xB);
    hipMemsetAsync(stats, 0, 256 * 4, stream);
    bn_stats_k<<<128, 128, 0, stream>>>(xB, 16384, stats);
    bn_apply_score_k<<<16384 / 4, 256, 0, stream>>>(xB, 16384, stats, bnl_g, bnl_b,
                                                    pool_w, scores);

    // ---- pool 0 (fused topk+gather+readout+CSR) ----
    topk_pool0_k<<<B_G, 128, 0, stream>>>(scores, xB, ei, ei + E_TOT, xp, rep0,
                                          row_start, row_end, colb, eidb);

    // ---- loop layer 1 (Fin=128, N=8192) ----
    tconv(xp, 8192, 128,
          cl_Wq + 65536, cl_bq + 512, cl_Wk + 65536, cl_bk + 512,
          cl_Wv + 65536, cl_bv + 512, cl_We + 8192,
          cl_Ws + 65536, cl_bs + 512, cl_Wb + 1536,
          tl_W + 65536, tl_b + 128, xB);
    hipMemsetAsync(stats, 0, 256 * 4, stream);
    bn_stats_k<<<128, 128, 0, stream>>>(xB, 8192, stats);
    bn_apply_score_k<<<8192 / 4, 256, 0, stream>>>(xB, 8192, stats, bnl_g + 128, bnl_b + 128,
                                                   pool_w + 128, scores);

    // ---- pool 1 (fused topk+readout) ----
    topk_pool1_k<<<B_G, 128, 0, stream>>>(scores, xB, rep1);

    // ---- MLP head (fp32 out) ----
    head_k<<<B_G, 256, 0, stream>>>(rep0, rep1, l1_W, l1_b, l2_W, l2_b, l3_W, l3_b, out);
}

// Round 8
// 874.189 us; speedup vs baseline: 2.0597x; 1.1351x over previous
//
#include <hip/hip_runtime.h>
#include <math.h>

#define E_TOT 65536
#define B_G   128
#define QLD   1664   // fused buffer row: [S(128) | Q/O(512) | K/outT0(512) | V/outT1(512)]

// ---------------- fused S/Q/K/V GEMM, 2 cols/thread (round-6 proven shape) ----------------
// grid (7, N/16), block 128. col0 = bx*256+tid, col1 = col0+128.
__global__ __launch_bounds__(128) void qkvs_gemm(
        const float* __restrict__ X, int ldX, int K, int kcs,
        const float* __restrict__ Wst,
        const float* __restrict__ Wq, const float* __restrict__ bq,
        const float* __restrict__ Wk, const float* __restrict__ bk,
        const float* __restrict__ Wv, const float* __restrict__ bv,
        float* __restrict__ out) {
    const int ROWS = 16, PAD = 20;
    __shared__ __align__(16) float xs[128 * PAD];
    int tid = threadIdx.x;
    int n0 = blockIdx.y * ROWS;
    int KC = 1 << kcs, kcm = KC - 1;

    int col0 = blockIdx.x * 256 + tid;
    int col1 = col0 + 128;
    bool act1 = col1 < 1664;

    const float* w0; const float* w1;
    int ld0, ld1;
    float b0 = 0.f, b1 = 0.f;
    {
        int c = col0;
        if (c < 128)       { w0 = Wst + c;          ld0 = 128; }
        else if (c < 640)  { w0 = Wq + (c - 128);   ld0 = 512; b0 = bq[c - 128]; }
        else if (c < 1152) { w0 = Wk + (c - 640);   ld0 = 512; b0 = bk[c - 640]; }
        else               { w0 = Wv + (c - 1152);  ld0 = 512; b0 = bv[c - 1152]; }
        c = act1 ? col1 : 0;
        if (c < 128)       { w1 = Wst + c;          ld1 = 128; }
        else if (c < 640)  { w1 = Wq + (c - 128);   ld1 = 512; b1 = bq[c - 128]; }
        else if (c < 1152) { w1 = Wk + (c - 640);   ld1 = 512; b1 = bk[c - 640]; }
        else               { w1 = Wv + (c - 1152);  ld1 = 512; b1 = bv[c - 1152]; }
    }

    float acc0[ROWS], acc1[ROWS];
#pragma unroll
    for (int r = 0; r < ROWS; ++r) { acc0[r] = b0; acc1[r] = b1; }

    for (int k0 = 0; k0 < K; k0 += KC) {
        for (int i = tid; i < ROWS * KC; i += 128) {
            int kk = i & kcm, r = i >> kcs;
            xs[kk * PAD + r] = X[(size_t)(n0 + r) * ldX + k0 + kk];
        }
        __syncthreads();
#pragma unroll 4
        for (int kk = 0; kk < KC; ++kk) {
            const float* xr = xs + kk * PAD;
            float xv[ROWS];
            float4* xvv = (float4*)xv;
            xvv[0] = *(const float4*)(xr);
            xvv[1] = *(const float4*)(xr + 4);
            xvv[2] = *(const float4*)(xr + 8);
            xvv[3] = *(const float4*)(xr + 12);
            float a = *w0; w0 += ld0;
            float b = *w1; w1 += ld1;
#pragma unroll
            for (int r = 0; r < ROWS; ++r) {
                acc0[r] = fmaf(xv[r], a, acc0[r]);
                acc1[r] = fmaf(xv[r], b, acc1[r]);
            }
        }
        __syncthreads();
    }
#pragma unroll
    for (int r = 0; r < ROWS; ++r) {
        out[(size_t)(n0 + r) * QLD + col0] = acc0[r];
        if (act1) out[(size_t)(n0 + r) * QLD + col1] = acc1[r];
    }
}

// ---------------- outT GEMM: partials of O @ tW into K (y=0) and V (y=1) regions -------------
// grid (N/16, 2), block 64 (1 wave), 2 cols/thread, ROWS=16 (low VGPR -> 9 waves/SIMD).
__global__ __launch_bounds__(64) void out_gemm(float* __restrict__ QB,
                                               const float* __restrict__ W) {
    const int ROWS = 16, PAD = 20, KC = 128;
    __shared__ __align__(16) float xs[KC * PAD];
    int tid = threadIdx.x;        // 64
    int n0 = blockIdx.x * ROWS;
    int kb = blockIdx.y * 256;
    int oo = blockIdx.y ? 1152 : 640;
    float acc0[ROWS], acc1[ROWS];
#pragma unroll
    for (int r = 0; r < ROWS; ++r) { acc0[r] = 0.f; acc1[r] = 0.f; }
    const float* wp0 = W + (size_t)kb * 128 + tid;
    const float* wp1 = wp0 + 64;
    for (int k0 = 0; k0 < 256; k0 += KC) {
        for (int i = tid; i < ROWS * KC; i += 64) {
            int kk = i & 127, r = i >> 7;
            xs[kk * PAD + r] = QB[(size_t)(n0 + r) * QLD + 128 + kb + k0 + kk];
        }
        __syncthreads();
#pragma unroll 4
        for (int kk = 0; kk < KC; ++kk) {
            const float* xr = xs + kk * PAD;
            float xv[ROWS];
            float4* xvv = (float4*)xv;
            xvv[0] = *(const float4*)(xr);
            xvv[1] = *(const float4*)(xr + 4);
            xvv[2] = *(const float4*)(xr + 8);
            xvv[3] = *(const float4*)(xr + 12);
            float w0 = *wp0; wp0 += 128;
            float w1 = *wp1; wp1 += 128;
#pragma unroll
            for (int r = 0; r < ROWS; ++r) {
                acc0[r] = fmaf(xv[r], w0, acc0[r]);
                acc1[r] = fmaf(xv[r], w1, acc1[r]);
            }
        }
        __syncthreads();
    }
#pragma unroll
    for (int r = 0; r < ROWS; ++r) {
        QB[(size_t)(n0 + r) * QLD + oo + tid]      = acc0[r];
        QB[(size_t)(n0 + r) * QLD + oo + tid + 64] = acc1[r];
    }
}

// ---------------- fused per-layer weight prep: Wst + ws_z + sbt + zb (warp per output) -------
__global__ void prep_k(const float* __restrict__ Ws, const float* __restrict__ bs,
                       const float* __restrict__ tW, const float* __restrict__ Wb,
                       int Fin, float* __restrict__ Wst, float* __restrict__ ws_z,
                       float* __restrict__ sbt, float* __restrict__ zb) {
    int w = (blockIdx.x * blockDim.x + threadIdx.x) >> 6;
    int lane = threadIdx.x & 63;
    int nW = Fin * 128;
    int total = nW + Fin + 128 + 1;
    if (w >= total) return;
    float s = 0.f;
    if (w < nW) {
        int f = w >> 7, m = w & 127;
        for (int c = lane; c < 512; c += 64)
            s = fmaf(Ws[(size_t)f * 512 + c], tW[(size_t)c * 128 + m], s);
    } else if (w < nW + Fin) {
        int f = w - nW;
        for (int c = lane; c < 512; c += 64)
            s = fmaf(Ws[(size_t)f * 512 + c], Wb[512 + c] - Wb[1024 + c], s);
    } else if (w < nW + Fin + 128) {
        int m = w - nW - Fin;
        for (int c = lane; c < 512; c += 64)
            s = fmaf(bs[c], tW[(size_t)c * 128 + m], s);
    } else {
        for (int c = lane; c < 512; c += 64)
            s = fmaf(bs[c], Wb[512 + c] - Wb[1024 + c], s);
    }
#pragma unroll
    for (int off = 32; off; off >>= 1) s += __shfl_xor(s, off, 64);
    if (lane == 0) {
        if (w < nW) Wst[w] = s;
        else if (w < nW + Fin) ws_z[w - nW] = s;
        else if (w < nW + Fin + 128) sbt[w - nW - Fin] = s;
        else zb[0] = s;
    }
}

// ---------------- per-graph CSR build (edges of graph g are [g*512,(g+1)*512)) --------------
__global__ __launch_bounds__(128) void csr_graph_k(const int* __restrict__ src,
                                                   const int* __restrict__ dst,
                                                   int* __restrict__ row_start,
                                                   int* __restrict__ row_end,
                                                   int* __restrict__ colb,
                                                   int* __restrict__ eidb) {
    __shared__ int cnt[128], pref[128], cur[128];
    int g = blockIdx.x, t = threadIdx.x;
    cnt[t] = 0;
    __syncthreads();
    int e0 = g * 512, nb = g * 128;
    int dl[4], sl[4];
#pragma unroll
    for (int i = 0; i < 4; ++i) {
        int e = e0 + t + i * 128;
        dl[i] = dst[e] - nb;
        sl[i] = src[e];
        atomicAdd(&cnt[dl[i]], 1);
    }
    __syncthreads();
    pref[t] = cnt[t];
    __syncthreads();
    for (int st = 1; st < 128; st <<= 1) {
        int v = (t >= st) ? pref[t - st] : 0;
        __syncthreads();
        pref[t] += v;
        __syncthreads();
    }
    int ex = pref[t] - cnt[t];
    row_start[nb + t] = e0 + ex;
    row_end[nb + t]   = e0 + pref[t];
    cur[t] = ex;
    __syncthreads();
#pragma unroll
    for (int i = 0; i < 4; ++i) {
        int pos = atomicAdd(&cur[dl[i]], 1);
        colb[e0 + pos] = sl[i];
        eidb[e0 + pos] = e0 + t + i * 128;
    }
}

// ---------------- all-heads attention on the fused buffer ----------------
template <int R>
__global__ void attn_all_k(float* __restrict__ B,
                           const int* __restrict__ row_start, const int* __restrict__ row_end,
                           const int* __restrict__ colb, const int* __restrict__ eidb,
                           const float* __restrict__ ea, const float* __restrict__ We,
                           const float* __restrict__ Wb, float* __restrict__ zOut4) {
    __shared__ float we_s[16 * 512];    // 32 KB
    int tid = threadIdx.x;
    int h = tid >> 6, lane = tid & 63;
    for (int i = tid; i < 16 * 512; i += 256) we_s[i] = We[i];
    __syncthreads();
    int c0 = h * 128 + lane, c1 = c0 + 64;
    float w13a = Wb[c0] + Wb[1024 + c0];
    float w13b = Wb[c1] + Wb[1024 + c1];
    int base = blockIdx.x * R;
    for (int r = 0; r < R; ++r) {
        int node = base + r;
        float* Qr = B + (size_t)node * QLD + 128;
        float q0 = Qr[c0], q1 = Qr[c1];
        float m = -INFINITY, l = 0.f, a0 = 0.f, a1 = 0.f;
        int beg = row_start[node], end = row_end[node];
        for (int j = beg; j < end; ++j) {
            int s = colb[j];
            int e = eidb[j];
            const float4* ea4 = (const float4*)(ea + (size_t)e * 16);
            float ev[16];
            float4* evv = (float4*)ev;
            evv[0] = ea4[0]; evv[1] = ea4[1]; evv[2] = ea4[2]; evv[3] = ea4[3];
            float e0 = 0.f, e1 = 0.f;
#pragma unroll
            for (int d = 0; d < 16; ++d) {
                e0 = fmaf(ev[d], we_s[d * 512 + c0], e0);
                e1 = fmaf(ev[d], we_s[d * 512 + c1], e1);
            }
            const float* Kr = B + (size_t)s * QLD + 640;
            const float* Vr = B + (size_t)s * QLD + 1152;
            float k0 = Kr[c0] + e0;
            float k1 = Kr[c1] + e1;
            float part = q0 * k0 + q1 * k1;
#pragma unroll
            for (int off = 32; off; off >>= 1) part += __shfl_xor(part, off, 64);
            float alpha = part * 0.08838834764831845f;  // 1/sqrt(128)
            float nm = fmaxf(m, alpha);
            float sc = expf(m - nm);      // 0 on first edge (m = -inf)
            float w  = expf(alpha - nm);
            l  = l * sc + w;
            a0 = a0 * sc + w * (Vr[c0] + e0);
            a1 = a1 * sc + w * (Vr[c1] + e1);
            m = nm;
        }
        float inv = 1.f / (l + 1e-16f);
        float o0 = a0 * inv, o1 = a1 * inv;
        Qr[c0] = o0;
        Qr[c1] = o1;
        float zp = o0 * w13a + o1 * w13b;
#pragma unroll
        for (int off = 32; off; off >>= 1) zp += __shfl_xor(zp, off, 64);
        if (lane == 0) zOut4[node * 4 + h] = zp;
    }
}

// ---------------- combine: x_next = relu(beta*(skipT+sbt) + (1-beta)*outT + tb) -------------
__global__ void combine_k(const float* __restrict__ x, int Fin,
                          const float* __restrict__ ws_z, const float* __restrict__ zb,
                          const float* __restrict__ zOut4, const float* __restrict__ B,
                          const float* __restrict__ sbt, const float* __restrict__ tb,
                          float* __restrict__ xn) {
    __shared__ float red[128];
    int node = blockIdx.x, t = threadIdx.x;  // 128
    red[t] = (t < Fin) ? x[(size_t)node * Fin + t] * ws_z[t] : 0.f;
    __syncthreads();
    for (int st = 64; st; st >>= 1) {
        if (t < st) red[t] += red[t + st];
        __syncthreads();
    }
    float z = zOut4[node * 4] + zOut4[node * 4 + 1] + zOut4[node * 4 + 2] + zOut4[node * 4 + 3]
            + red[0] + zb[0];
    float beta = 1.f / (1.f + expf(-z));
    const float* row = B + (size_t)node * QLD;
    float outT = row[640 + t] + row[1152 + t];
    float a = beta * (row[t] + sbt[t]) + (1.f - beta) * outT + tb[t];
    xn[(size_t)node * 128 + t] = fmaxf(a, 0.f);
}

// ---------------- batchnorm ----------------
__global__ void bn_stats_k(const float* __restrict__ x, int N, float* __restrict__ stats) {
    int c = threadIdx.x;  // 128
    float s = 0.f, ss = 0.f;
    for (int n = blockIdx.x; n < N; n += gridDim.x) {
        float v = x[(size_t)n * 128 + c];
        s += v; ss += v * v;
    }
    atomicAdd(&stats[c], s);
    atomicAdd(&stats[128 + c], ss);
}

__global__ void bn_apply_k(float* __restrict__ x, int N, const float* __restrict__ stats,
                           const float* __restrict__ g, const float* __restrict__ b) {
    int idx = blockIdx.x * blockDim.x + threadIdx.x;
    if (idx >= N * 128) return;
    int c = idx & 127;
    float m = stats[c] / (float)N;
    float var = fmaxf(stats[128 + c] / (float)N - m * m, 0.f);
    float inv = rsqrtf(var + 1e-5f);
    x[idx] = g[c] * (x[idx] - m) * inv + b[c];
}

// bn apply + pooling score in one pass (wave = node). grid N/4, block 256.
__global__ void bn_apply_score_k(float* __restrict__ x, int N, const float* __restrict__ stats,
                                 const float* __restrict__ g, const float* __restrict__ b,
                                 const float* __restrict__ w, float* __restrict__ s) {
    int node = blockIdx.x * 4 + (threadIdx.x >> 6);
    int lane = threadIdx.x & 63;
    int c0 = lane, c1 = lane + 64;
    float m0 = stats[c0] / (float)N;
    float v0 = fmaxf(stats[128 + c0] / (float)N - m0 * m0, 0.f);
    float m1 = stats[c1] / (float)N;
    float v1 = fmaxf(stats[128 + c1] / (float)N - m1 * m1, 0.f);
    float* row = x + (size_t)node * 128;
    float x0 = g[c0] * (row[c0] - m0) * rsqrtf(v0 + 1e-5f) + b[c0];
    float x1 = g[c1] * (row[c1] - m1) * rsqrtf(v1 + 1e-5f) + b[c1];
    row[c0] = x0;
    row[c1] = x1;
    float w0 = w[c0], w1 = w[c1];
    float p  = x0 * w0 + x1 * w1;
    float nw = w0 * w0 + w1 * w1;
#pragma unroll
    for (int off = 32; off; off >>= 1) {
        p  += __shfl_xor(p, off, 64);
        nw += __shfl_xor(nw, off, 64);
    }
    if (lane == 0) s[node] = p / sqrtf(nw);
}

// ---------------- pool0: topk + gather + readout + per-graph CSR rebuild --------------------
__global__ __launch_bounds__(128) void topk_pool0_k(
        const float* __restrict__ sc, const float* __restrict__ x,
        const int* __restrict__ src, const int* __restrict__ dst,
        float* __restrict__ xp, float* __restrict__ rep,
        int* __restrict__ row_start, int* __restrict__ row_end,
        int* __restrict__ colb, int* __restrict__ eidb) {
    __shared__ float ls[128], th[64];
    __shared__ int lk[128], rk[128], oon[64];
    __shared__ int cnt[64], pref[64], cur[64];
    int g = blockIdx.x, t = threadIdx.x;
    float val = sc[g * 128 + t];
    ls[t] = val;
    __syncthreads();
    int c = 0;
    for (int j = 0; j < 128; ++j) {
        float vj = ls[j];
        c += (vj > val || (vj == val && j < t)) ? 1 : 0;
    }
    int kp = (c < 64) ? 1 : 0;
    lk[t] = kp;
    __syncthreads();
    int r = 0;
    for (int j = 0; j < t; ++j) r += lk[j];
    rk[t] = r;
    if (kp) { oon[r] = t; th[r] = tanhf(val); }
    __syncthreads();
    float mx = -INFINITY, sm = 0.f;
    for (int rr = 0; rr < 64; ++rr) {
        float v = x[(size_t)(g * 128 + oon[rr]) * 128 + t] * th[rr];
        xp[(size_t)(g * 64 + rr) * 128 + t] = v;
        mx = fmaxf(mx, v);
        sm += v;
    }
    rep[g * 256 + t] = mx;
    rep[g * 256 + 128 + t] = sm * (1.f / 64.f);
    if (t < 64) cnt[t] = 0;
    __syncthreads();
    int e0 = g * 512, nb = g * 128;
    int keepE[4], dr[4], sr[4];
#pragma unroll
    for (int i = 0; i < 4; ++i) {
        int e = e0 + t + i * 128;
        int s_ = src[e] - nb, d_ = dst[e] - nb;
        int ke = lk[s_] && lk[d_];
        keepE[i] = ke;
        dr[i] = rk[d_];
        sr[i] = rk[s_];
        if (ke) atomicAdd(&cnt[dr[i]], 1);
    }
    __syncthreads();
    if (t < 64) pref[t] = cnt[t];
    __syncthreads();
    for (int st = 1; st < 64; st <<= 1) {
        int v = (t < 64 && t >= st) ? pref[t - st] : 0;
        __syncthreads();
        if (t < 64) pref[t] += v;
        __syncthreads();
    }
    if (t < 64) {
        int ex = pref[t] - cnt[t];
        row_start[g * 64 + t] = e0 + ex;
        row_end[g * 64 + t]   = e0 + pref[t];
        cur[t] = ex;
    }
    __syncthreads();
#pragma unroll
    for (int i = 0; i < 4; ++i) {
        if (keepE[i]) {
            int pos = atomicAdd(&cur[dr[i]], 1);
            colb[e0 + pos] = g * 64 + sr[i];
            eidb[e0 + pos] = e0 + t + i * 128;
        }
    }
}

// ---------------- pool1: topk + readout only. n=64 -> k=32. block 128. ----------------------
__global__ __launch_bounds__(128) void topk_pool1_k(
        const float* __restrict__ sc, const float* __restrict__ x,
        float* __restrict__ rep) {
    __shared__ float ls[64], th[32];
    __shared__ int lk[64], oon[32];
    int g = blockIdx.x, t = threadIdx.x;
    float val = 0.f;
    if (t < 64) { val = sc[g * 64 + t]; ls[t] = val; }
    __syncthreads();
    if (t < 64) {
        int c = 0;
        for (int j = 0; j < 64; ++j) {
            float vj = ls[j];
            c += (vj > val || (vj == val && j < t)) ? 1 : 0;
        }
        int kp = (c < 32) ? 1 : 0;
        lk[t] = kp;
    }
    __syncthreads();
    if (t < 64 && lk[t]) {
        int r = 0;
        for (int j = 0; j < t; ++j) r += lk[j];
        oon[r] = t;
        th[r] = tanhf(val);
    }
    __syncthreads();
    float mx = -INFINITY, sm = 0.f;
    for (int rr = 0; rr < 32; ++rr) {
        float v = x[(size_t)(g * 64 + oon[rr]) * 128 + t] * th[rr];
        mx = fmaxf(mx, v);
        sm += v;
    }
    rep[g * 256 + t] = mx;
    rep[g * 256 + 128 + t] = sm * (1.f / 32.f);
}

// ---------------- MLP head: one block per graph, fp32 output ----------------
__global__ void head_k(const float* __restrict__ rep0, const float* __restrict__ rep1,
                       const float* __restrict__ W1, const float* __restrict__ b1,
                       const float* __restrict__ W2, const float* __restrict__ b2,
                       const float* __restrict__ W3, const float* __restrict__ b3,
                       float* __restrict__ out) {
    __shared__ float h[256], a1[256], a2[128], red[256];
    int g = blockIdx.x, t = threadIdx.x;  // 256
    h[t] = rep0[g * 256 + t] + rep1[g * 256 + t];
    __syncthreads();
    float acc = b1[t];
    for (int i = 0; i < 256; ++i) acc = fmaf(h[i], W1[i * 256 + t], acc);
    a1[t] = fmaxf(acc, 0.f);
    __syncthreads();
    if (t < 128) {
        float a = b2[t];
        for (int i = 0; i < 256; ++i) a = fmaf(a1[i], W2[i * 128 + t], a);
        a2[t] = fmaxf(a, 0.f);
    }
    __syncthreads();
    red[t] = (t < 128) ? a2[t] * W3[t] : 0.f;
    __syncthreads();
    for (int st = 128; st; st >>= 1) {
        if (t < st) red[t] += red[t + st];
        __syncthreads();
    }
    if (t == 0) out[g] = red[0] + b3[0];
}

// ======================================================================================
extern "C" void kernel_launch(void* const* d_in, const int* in_sizes, int n_in,
                              void* d_out, int out_size, void* d_ws, size_t ws_size,
                              hipStream_t stream) {
    (void)in_sizes; (void)n_in; (void)out_size; (void)ws_size;

    const float* x0    = (const float*)d_in[0];
    const int*   ei    = (const int*)d_in[1];
    const float* ea    = (const float*)d_in[2];
    const float* c1_Wq = (const float*)d_in[3];
    const float* c1_bq = (const float*)d_in[4];
    const float* c1_Wk = (const float*)d_in[5];
    const float* c1_bk = (const float*)d_in[6];
    const float* c1_Wv = (const float*)d_in[7];
    const float* c1_bv = (const float*)d_in[8];
    const float* c1_We = (const float*)d_in[9];
    const float* c1_Ws = (const float*)d_in[10];
    const float* c1_bs = (const float*)d_in[11];
    const float* c1_Wb = (const float*)d_in[12];
    const float* t1_W  = (const float*)d_in[13];
    const float* t1_b  = (const float*)d_in[14];
    const float* bn1_g = (const float*)d_in[15];
    const float* bn1_b = (const float*)d_in[16];
    const float* cl_Wq = (const float*)d_in[17];
    const float* cl_bq = (const float*)d_in[18];
    const float* cl_Wk = (const float*)d_in[19];
    const float* cl_bk = (const float*)d_in[20];
    const float* cl_Wv = (const float*)d_in[21];
    const float* cl_bv = (const float*)d_in[22];
    const float* cl_We = (const float*)d_in[23];
    const float* cl_Ws = (const float*)d_in[24];
    const float* cl_bs = (const float*)d_in[25];
    const float* cl_Wb = (const float*)d_in[26];
    const float* tl_W  = (const float*)d_in[27];
    const float* tl_b  = (const float*)d_in[28];
    const float* bnl_g = (const float*)d_in[29];
    const float* bnl_b = (const float*)d_in[30];
    const float* pool_w= (const float*)d_in[31];
    const float* l1_W  = (const float*)d_in[32];
    const float* l1_b  = (const float*)d_in[33];
    const float* l2_W  = (const float*)d_in[34];
    const float* l2_b  = (const float*)d_in[35];
    const float* l3_W  = (const float*)d_in[36];
    const float* l3_b  = (const float*)d_in[37];
    float* out = (float*)d_out;

    // -------- workspace layout (~127 MB) --------
    char* base = (char*)d_ws;
    size_t off = 0;
    auto alloc = [&](size_t bytes) -> void* {
        void* p = base + off;
        off += (bytes + 255) & ~(size_t)255;
        return p;
    };
    float* QB   = (float*)alloc((size_t)16384 * QLD * 4);   // 109 MB
    float* xA   = (float*)alloc((size_t)16384 * 128 * 4);
    float* xB   = (float*)alloc((size_t)16384 * 128 * 4);
    float* zOut4= (float*)alloc((size_t)16384 * 4 * 4);
    float* Wst  = (float*)alloc(128 * 128 * 4);
    float* ws_z = (float*)alloc(128 * 4);
    float* sbt  = (float*)alloc(128 * 4);
    float* zb   = (float*)alloc(4 * 4);
    float* stats  = (float*)alloc(256 * 4);
    float* scores = (float*)alloc(16384 * 4);
    float* rep0   = (float*)alloc(128 * 256 * 4);
    float* rep1   = (float*)alloc(128 * 256 * 4);
    int* row_start = (int*)alloc(16384 * 4);
    int* row_end   = (int*)alloc(16384 * 4);
    int* colb      = (int*)alloc(E_TOT * 4);
    int* eidb      = (int*)alloc(E_TOT * 4);
    float* xp = xA;  // alias: xA dead once loop-0's combine has consumed it

    // Full tconv + t-layer(+bias+relu): xn = relu(gated @ tW + tb)
    auto tconv = [&](const float* xin, int N, int Fin,
                     const float* Wq, const float* bq, const float* Wk, const float* bk,
                     const float* Wv, const float* bv, const float* We,
                     const float* Ws, const float* bs, const float* Wb,
                     const float* tW, const float* tb, float* xn) {
        int totW = Fin * 128 + Fin + 128 + 1;
        prep_k<<<(totW + 3) / 4, 256, 0, stream>>>(Ws, bs, tW, Wb, Fin, Wst, ws_z, sbt, zb);
        int kcs = (Fin == 64) ? 6 : 7;
        qkvs_gemm<<<dim3(7, N / 16), 128, 0, stream>>>(xin, Fin, Fin, kcs,
                                                       Wst, Wq, bq, Wk, bk, Wv, bv, QB);
        attn_all_k<8><<<N / 8, 256, 0, stream>>>(QB, row_start, row_end, colb, eidb,
                                                 ea, We, Wb, zOut4);
        out_gemm<<<dim3(N / 16, 2), 64, 0, stream>>>(QB, tW);
        combine_k<<<N, 128, 0, stream>>>(xin, Fin, ws_z, zb, zOut4, QB, sbt, tb, xn);
    };

    // ---- CSR over original edges (per-graph, one kernel) ----
    csr_graph_k<<<B_G, 128, 0, stream>>>(ei, ei + E_TOT, row_start, row_end, colb, eidb);

    // ---- layer 1: tconv(Fin=64) + t1 + bn1 ----
    tconv(x0, 16384, 64, c1_Wq, c1_bq, c1_Wk, c1_bk, c1_Wv, c1_bv, c1_We,
          c1_Ws, c1_bs, c1_Wb, t1_W, t1_b, xA);
    hipMemsetAsync(stats, 0, 256 * 4, stream);
    bn_stats_k<<<128, 128, 0, stream>>>(xA, 16384, stats);
    bn_apply_k<<<(16384 * 128 + 255) / 256, 256, 0, stream>>>(xA, 16384, stats, bn1_g, bn1_b);

    // ---- loop layer 0 (Fin=128, N=16384) ----
    tconv(xA, 16384, 128, cl_Wq, cl_bq, cl_Wk, cl_bk, cl_Wv, cl_bv, cl_We,
          cl_Ws, cl_bs, cl_Wb, tl_W, tl_b, xB);
    hipMemsetAsync(stats, 0, 256 * 4, stream);
    bn_stats_k<<<128, 128, 0, stream>>>(xB, 16384, stats);
    bn_apply_score_k<<<16384 / 4, 256, 0, stream>>>(xB, 16384, stats, bnl_g, bnl_b,
                                                    pool_w, scores);

    // ---- pool 0 (fused topk+gather+readout+CSR) ----
    topk_pool0_k<<<B_G, 128, 0, stream>>>(scores, xB, ei, ei + E_TOT, xp, rep0,
                                          row_start, row_end, colb, eidb);

    // ---- loop layer 1 (Fin=128, N=8192) ----
    tconv(xp, 8192, 128,
          cl_Wq + 65536, cl_bq + 512, cl_Wk + 65536, cl_bk + 512,
          cl_Wv + 65536, cl_bv + 512, cl_We + 8192,
          cl_Ws + 65536, cl_bs + 512, cl_Wb + 1536,
          tl_W + 65536, tl_b + 128, xB);
    hipMemsetAsync(stats, 0, 256 * 4, stream);
    bn_stats_k<<<128, 128, 0, stream>>>(xB, 8192, stats);
    bn_apply_score_k<<<8192 / 4, 256, 0, stream>>>(xB, 8192, stats, bnl_g + 128, bnl_b + 128,
                                                   pool_w + 128, scores);

    // ---- pool 1 (fused topk+readout) ----
    topk_pool1_k<<<B_G, 128, 0, stream>>>(scores, xB, rep1);

    // ---- MLP head (fp32 out) ----
    head_k<<<B_G, 256, 0, stream>>>(rep0, rep1, l1_W, l1_b, l2_W, l2_b, l3_W, l3_b, out);
}